// Round 18
// baseline (165.989 us; speedup 1.0000x reference)
//
#include <hip/hip_runtime.h>
#include <hip/hip_bf16.h>
#include <math.h>

typedef __attribute__((ext_vector_type(8))) short bf16x8;
typedef __attribute__((ext_vector_type(4))) short bf16x4;
typedef __attribute__((ext_vector_type(4))) float f32x4;
typedef __attribute__((ext_vector_type(16))) float f32x16;
typedef __attribute__((ext_vector_type(4))) unsigned u32x4;
typedef __attribute__((ext_vector_type(2))) unsigned u32x2;
typedef __attribute__((ext_vector_type(4))) int i32x4;

#define DEV static __device__ __forceinline__
#define LOG2E 1.4426950408889634f
#define INV2PI 0.15915494309189535f

DEV unsigned short f2bf(float f) {
  unsigned int u = __float_as_uint(f);
  u += 0x7FFFu + ((u >> 16) & 1u);   // RNE, inputs finite
  return (unsigned short)(u >> 16);
}
DEV float bf2f(unsigned short h) { return __uint_as_float(((unsigned int)h) << 16); }
DEV unsigned cvtpk(float lo, float hi) {
  unsigned r;
  asm("v_cvt_pk_bf16_f32 %0, %1, %2" : "=v"(r) : "v"(lo), "v"(hi));
  return r;
}
DEV float exp2raw(float x) {            // inputs in [-30,0]: no fixup needed
  float r;
  asm("v_exp_f32 %0, %1" : "=v"(r) : "v"(x));
  return r;
}
DEV float fract_raw(float x) { float r; asm("v_fract_f32 %0, %1" : "=v"(r) : "v"(x)); return r; }
DEV float sin_rev(float x)   { float r; asm("v_sin_f32 %0, %1"   : "=v"(r) : "v"(x)); return r; }
DEV float cos_rev(float x)   { float r; asm("v_cos_f32 %0, %1"   : "=v"(r) : "v"(x)); return r; }
DEV float wsum(float v) { for (int o = 32; o; o >>= 1) v += __shfl_xor(v, o); return v; }
DEV float wmaxr(float v) { for (int o = 32; o; o >>= 1) v = fmaxf(v, __shfl_xor(v, o)); return v; }

// async global->LDS, 16B per lane; dest = wave-uniform base + lane*16
DEV void gload_lds16(const void* g, void* s) {
  __builtin_amdgcn_global_load_lds(
      (const __attribute__((address_space(1))) unsigned int*)g,
      (__attribute__((address_space(3))) unsigned int*)s, 16, 0, 0);
}

// ---------- k1: blocks [0,4096) per-row |w| sums; [4096,4608) ada ----------
__global__ __launch_bounds__(256) void wrada_k(const float* __restrict__ qw,
                                               const float* __restrict__ ow,
                                               const float* __restrict__ cond,
                                               const float* __restrict__ nw,
                                               float* __restrict__ rowsum,
                                               float* __restrict__ ada) {
  if (blockIdx.x < 4096) {
    int row = blockIdx.x;  // 0..3071 -> qkv_w, 3072..4095 -> out_w
    const float* p = (row < 3072) ? (qw + (size_t)row * 1024)
                                  : (ow + (size_t)(row - 3072) * 1024);
    f32x4 v = *(const f32x4*)&p[threadIdx.x * 4];
    float s = fabsf(v[0]) + fabsf(v[1]) + fabsf(v[2]) + fabsf(v[3]);
    s = wsum(s);
    __shared__ float sh[4];
    if ((threadIdx.x & 63) == 0) sh[threadIdx.x >> 6] = s;
    __syncthreads();
    if (threadIdx.x == 0) rowsum[row] = sh[0] + sh[1] + sh[2] + sh[3];
  } else {
    int bid2 = blockIdx.x - 4096;          // 0..511
    int b = bid2 >> 8;
    int j = (bid2 & 255) * 4 + (threadIdx.x >> 6);
    int l = threadIdx.x & 63;
    const float* cp = cond + b * 1024;
    const float* wp = nw + (size_t)j * 1024;
    float s = 0.f;
    for (int c = l; c < 1024; c += 64) s += cp[c] * wp[c];
    s = wsum(s);
    if (l == 0) ada[b * 1024 + j] = 1.f + s;
  }
}

__global__ __launch_bounds__(256) void finalize_k(const float* __restrict__ rowsum,
                                                  float* __restrict__ scales) {
  float s1 = 0.f, s2 = 0.f;
  for (int i = threadIdx.x; i < 3072; i += 256) s1 += rowsum[i];
  for (int i = threadIdx.x; i < 1024; i += 256) s2 += rowsum[3072 + i];
  s1 = wsum(s1); s2 = wsum(s2);
  __shared__ float sh1[4], sh2[4];
  if ((threadIdx.x & 63) == 0) { sh1[threadIdx.x >> 6] = s1; sh2[threadIdx.x >> 6] = s2; }
  __syncthreads();
  if (threadIdx.x == 0) {
    float m1 = fmaxf((sh1[0] + sh1[1] + sh1[2] + sh1[3]) / (3072.f * 1024.f), 1e-5f);
    float m2 = fmaxf((sh2[0] + sh2[1] + sh2[2] + sh2[3]) / (1024.f * 1024.f), 1e-5f);
    scales[0] = m1; scales[1] = 1.f / m1;   // qkv_w: mean, 1/mean
    scales[2] = m2; scales[3] = 1.f / m2;   // out_w
  }
}

// ---------- k2: blocks [0,4096) ternary wquant -> i8; [4096,8192) RMSNorm+act_quant ----------
__global__ __launch_bounds__(256) void wqrms_k(const float* __restrict__ qw,
                                               const float* __restrict__ ow,
                                               const float* __restrict__ scales,
                                               const float* __restrict__ x,
                                               const float* __restrict__ ada,
                                               signed char* __restrict__ Wq,
                                               signed char* __restrict__ Wo,
                                               signed char* __restrict__ Aq,
                                               float* __restrict__ ascale) {
  if (blockIdx.x < 4096) {
    int i0 = (blockIdx.x * 256 + threadIdx.x) * 4;
    if (i0 < 3072 * 1024) {
      f32x4 v = *(const f32x4*)&qw[i0];
      unsigned pk = 0;
      for (int j = 0; j < 4; j++) {
        int t = (int)fminf(fmaxf(rintf(v[j] * scales[1]), -1.f), 1.f);
        pk |= ((unsigned)t & 0xFFu) << (8 * j);
      }
      *(unsigned*)&Wq[i0] = pk;
    } else {
      int k = i0 - 3072 * 1024;
      f32x4 v = *(const f32x4*)&ow[k];
      unsigned pk = 0;
      for (int j = 0; j < 4; j++) {
        int t = (int)fminf(fmaxf(rintf(v[j] * scales[3]), -1.f), 1.f);
        pk |= ((unsigned)t & 0xFFu) << (8 * j);
      }
      *(unsigned*)&Wo[k] = pk;
    }
  } else {
    int row = blockIdx.x - 4096;   // b*2048 + t
    int b = row >> 11;
    const float* xr = x + (size_t)row * 1024;
    const float* ar = ada + b * 1024;
    int t4 = threadIdx.x * 4;
    f32x4 v = *(const f32x4*)&xr[t4];
    float ss = v[0]*v[0] + v[1]*v[1] + v[2]*v[2] + v[3]*v[3];
    ss = wsum(ss);
    __shared__ float sh[4], sh2[4];
    if ((threadIdx.x & 63) == 0) sh[threadIdx.x >> 6] = ss;
    __syncthreads();
    float inv = rsqrtf((sh[0] + sh[1] + sh[2] + sh[3]) * (1.f / 1024.f) + 1e-6f);
    f32x4 a = *(const f32x4*)&ar[t4];
    float xn[4]; float mx = 0.f;
    for (int i = 0; i < 4; i++) { xn[i] = v[i] * a[i] * inv; mx = fmaxf(mx, fabsf(xn[i])); }
    mx = wmaxr(mx);
    if ((threadIdx.x & 63) == 0) sh2[threadIdx.x >> 6] = mx;
    __syncthreads();
    float rmax = fmaxf(fmaxf(sh2[0], sh2[1]), fmaxf(sh2[2], sh2[3]));
    float s = 127.f / fmaxf(rmax, 1e-5f);
    unsigned pk = 0;
    for (int i = 0; i < 4; i++) {
      int ai = (int)fminf(fmaxf(rintf(xn[i] * s), -128.f), 127.f);
      pk |= ((unsigned)ai & 0xFFu) << (8 * i);
    }
    *(unsigned*)&Aq[(size_t)row * 1024 + t4] = pk;
    if (threadIdx.x == 0) ascale[row] = 1.f / s;
  }
}

// ---------- combine split-K partials + act_quant -> int8 ----------
__global__ __launch_bounds__(256) void oquant_k(const unsigned short* __restrict__ Opart,
                                                const float* __restrict__ ms,
                                                signed char* __restrict__ Oq,
                                                float* __restrict__ oscale) {
  int row = blockIdx.x;            // b*2048 + t
  int b = row >> 11, qrow = row & 2047;
  int t4 = threadIdx.x * 4;
  int h = t4 >> 6, e0 = t4 & 63;
  int bh = b * 16 + h;
  size_t i0 = (size_t)bh * 2048 + qrow;             // split 0
  size_t i1 = (size_t)(32 + bh) * 2048 + qrow;      // split 1
  float w = 1.f / (ms[i0] + ms[i1]);                // common 2^-15 factor cancels
  bf16x4 o0 = *(const bf16x4*)&Opart[i0 * 64 + e0];
  bf16x4 o1 = *(const bf16x4*)&Opart[i1 * 64 + e0];
  float v[4]; float mx = 0.f;
  for (int i = 0; i < 4; i++) {
    v[i] = (bf2f((unsigned short)o0[i]) + bf2f((unsigned short)o1[i])) * w;
    mx = fmaxf(mx, fabsf(v[i]));
  }
  mx = wmaxr(mx);
  __shared__ float sh[4];
  if ((threadIdx.x & 63) == 0) sh[threadIdx.x >> 6] = mx;
  __syncthreads();
  float rmax = fmaxf(fmaxf(sh[0], sh[1]), fmaxf(sh[2], sh[3]));
  float s = 127.f / fmaxf(rmax, 1e-5f);
  float is = 1.f / s;
  unsigned pk = 0;
  for (int i = 0; i < 4; i++) {
    int ai = (int)fminf(fmaxf(rintf(v[i] * s), -128.f), 127.f);
    pk |= ((unsigned)ai & 0xFFu) << (8 * i);
  }
  *(unsigned*)&Oq[(size_t)row * 1024 + t4] = pk;
  if (threadIdx.x == 0) oscale[row] = is;
}

// ---------- i8 GEMM: double-buffered LDS, ONE barrier per K-iter ----------
// C[M][N] = (A8 . B8^T) * rowsc[row] * wsc; 128x128 tile, BK=64, i32-exact accum.
__global__ __launch_bounds__(256, 3) void gemm_i8(const signed char* __restrict__ A8,
                                                  const signed char* __restrict__ B8,
                                                  int N, int K, int nwg, int mode,
                                                  const float* __restrict__ rowsc,
                                                  const float* __restrict__ wscp,
                                                  const float* __restrict__ skip,
                                                  float* __restrict__ outF,
                                                  unsigned short* __restrict__ outB) {
  __shared__ signed char As[2][128 * 64];
  __shared__ signed char Bs[2][128 * 64];
  int bid = blockIdx.x;
  int wg = (bid % 8) * (nwg >> 3) + (bid >> 3);   // XCD-chunked remap
  int bx = wg & 31, by = wg >> 5;                 // M=4096 -> 32 M-tiles
  int tid = threadIdx.x;
  int w = tid >> 6, l = tid & 63;
  int q = l & 15, g = l >> 4;
  int tm = bx * 128, tn = by * 128;
  int wr = w >> 1, wc = w & 1;
  float wsc = wscp[0];
  i32x4 acc[4][4];
  i32x4 zero = {0, 0, 0, 0};
#pragma unroll
  for (int m = 0; m < 4; m++)
#pragma unroll
    for (int n = 0; n < 4; n++) acc[m][n] = zero;
  int s0 = w * 64 + l, s1 = 256 + s0;
  int r0 = s0 >> 2, p0 = s0 & 3, gs0 = p0 ^ ((r0 >> 1) & 3);
  int r1 = s1 >> 2, p1 = s1 & 3, gs1 = p1 ^ ((r1 >> 1) & 3);
  const signed char* Ag0 = A8 + (size_t)(tm + r0) * K + gs0 * 16;
  const signed char* Ag1 = A8 + (size_t)(tm + r1) * K + gs1 * 16;
  const signed char* Bg0 = B8 + (size_t)(tn + r0) * K + gs0 * 16;
  const signed char* Bg1 = B8 + (size_t)(tn + r1) * K + gs1 * 16;
  int posq = ((q >> 1) & 3);

  auto stage = [&](int buf, int k0) {
    gload_lds16(Ag0 + k0, &As[buf][w * 1024]);
    gload_lds16(Ag1 + k0, &As[buf][4096 + w * 1024]);
    gload_lds16(Bg0 + k0, &Bs[buf][w * 1024]);
    gload_lds16(Bg1 + k0, &Bs[buf][4096 + w * 1024]);
  };

  stage(0, 0);
  __syncthreads();
  int cur = 0;
  for (int k0 = 0; k0 < K; k0 += 64) {
    if (k0 + 64 < K) stage(cur ^ 1, k0 + 64);     // prefetch overlaps MFMA
    int pg = (g ^ posq) * 16;
    i32x4 af[4], bfr[4];
#pragma unroll
    for (int m = 0; m < 4; m++)
      af[m] = *(const i32x4*)&As[cur][(wr * 64 + m * 16 + q) * 64 + pg];
#pragma unroll
    for (int n = 0; n < 4; n++)
      bfr[n] = *(const i32x4*)&Bs[cur][(wc * 64 + n * 16 + q) * 64 + pg];
#pragma unroll
    for (int m = 0; m < 4; m++)
#pragma unroll
      for (int n = 0; n < 4; n++)
        acc[m][n] = __builtin_amdgcn_mfma_i32_16x16x64_i8(af[m], bfr[n], acc[m][n], 0, 0, 0);
    __syncthreads();      // all waves done reading cur; prefetch vmcnt drained
    cur ^= 1;
  }
#pragma unroll
  for (int m = 0; m < 4; m++) {
#pragma unroll
    for (int r = 0; r < 4; r++) {
      int row = tm + wr * 64 + m * 16 + g * 4 + r;
      float dq = rowsc[row] * wsc;
#pragma unroll
      for (int n = 0; n < 4; n++) {
        int col = tn + wc * 64 + n * 16 + q;
        float vv = (float)acc[m][n][r] * dq;
        if (mode == 0) outB[(size_t)row * N + col] = f2bf(vv);
        else { size_t idx = (size_t)row * N + col; outF[idx] = vv + skip[idx]; }
      }
    }
  }
}

// ---------- fused prep v2: blocks [0,4096) = qk-norm+RoPE (vectorized bf16x8);
//                          [4096,5120) = V transpose ----------
// RoPE block = one token: threads 0-127 Q-row, 128-255 K-row; thread = 8 contiguous
// elems of one head (head = 8-lane group). Norm: shfl_xor(1,2,4) group reduce.
// Partner (e+-24) = lane +-3 in group.
__global__ __launch_bounds__(256) void prep_k(const unsigned short* __restrict__ qkv,
                                              const float* __restrict__ pos,
                                              const float* __restrict__ scale,
                                              const float* __restrict__ freqs,
                                              unsigned short* __restrict__ Qo,
                                              unsigned short* __restrict__ Ko,
                                              unsigned short* __restrict__ VT) {
  __shared__ unsigned short tile[64][72];
  int tid = threadIdx.x;
  if (blockIdx.x < 4096) {
    int t = blockIdx.x & 2047, b = blockIdx.x >> 11;
    int half = tid >> 7;            // 0 = Q, 1 = K
    int i = tid & 127;
    int h = i >> 3, j = i & 7;      // head, 8-elem slot (e = j*8..j*8+7)
    int lane = tid & 63;
    const unsigned short* src =
        qkv + ((size_t)(b * 2048 + t)) * 3072 + half * 1024 + h * 64 + j * 8;
    bf16x8 vv = *(const bf16x8*)src;
    float f[8]; float ss = 0.f;
#pragma unroll
    for (int m = 0; m < 8; m++) { f[m] = bf2f((unsigned short)vv[m]); ss += f[m] * f[m]; }
    ss += __shfl_xor(ss, 1);
    ss += __shfl_xor(ss, 2);
    ss += __shfl_xor(ss, 4);        // full-head sum (8 lanes x 8 elems)
    float fac = sqrtf(scale[h]) * rsqrtf(ss + 1e-6f);
#pragma unroll
    for (int m = 0; m < 8; m++) f[m] *= fac;
    // partner exchange: e<24 -> e+24 (lane+3), 24<=e<48 -> e-24 (lane-3)
    int plane = (j < 3) ? lane + 3 : ((j < 6) ? lane - 3 : lane);
    float p[8];
#pragma unroll
    for (int m = 0; m < 8; m++) p[m] = __shfl(f[m], plane);
    float outv[8];
    if (j < 6) {
      int a = (j < 3) ? j : j - 3;
      float sgn = (j < 3) ? -1.f : 1.f;
      float pth = pos[((size_t)(b * 2048 + t)) * 3 + a];
      f32x4 fr0 = *(const f32x4*)&freqs[h * 8];
      f32x4 fr1 = *(const f32x4*)&freqs[h * 8 + 4];
#pragma unroll
      for (int m = 0; m < 8; m++) {
        float frq = (m < 4) ? fr0[m] : fr1[m - 4];
        float rev = fract_raw(pth * frq * INV2PI);   // sin(2*pi*rev) == sin(th)
        float sn = sin_rev(rev), cs = cos_rev(rev);
        outv[m] = f[m] * cs + sgn * p[m] * sn;
      }
    } else {
#pragma unroll
      for (int m = 0; m < 8; m++) outv[m] = f[m];
    }
    bf16x8 o;
    size_t oi = ((size_t)((b * 16 + h) * 2048 + t)) * 64 + j * 8;
    if (half == 0) {
#pragma unroll
      for (int m = 0; m < 8; m++) o[m] = (short)f2bf(outv[m] * LOG2E);  // exp2-softmax prescale
      *(bf16x8*)(Qo + oi) = o;
    } else {
#pragma unroll
      for (int m = 0; m < 8; m++) o[m] = (short)f2bf(outv[m]);
      *(bf16x8*)(Ko + oi) = o;
    }
  } else {
    // V transpose: VT[b][h][e][t'], t' = bits2<->3 swap (bakes PV k-perm)
    int bid2 = blockIdx.x - 4096;
    int tt = bid2 & 31, bh = bid2 >> 5;
    int b = bh >> 4, h = bh & 15;
    for (int ro = 0; ro < 2; ro++) {
      int r = ro * 32 + (tid >> 3);
      int c = (tid & 7) * 8;
      *(bf16x8*)&tile[r][c] =
          *(const bf16x8*)(qkv + ((size_t)(b * 2048 + tt * 64 + r)) * 3072 + 2048 + h * 64 + c);
    }
    __syncthreads();
    int e = tid >> 2;
    int tc = (tid & 3) * 16;
    bf16x8 o0, o1;
#pragma unroll
    for (int i = 0; i < 4; i++) {
      o0[i]     = (short)tile[tc + i][e];
      o0[4 + i] = (short)tile[tc + 8 + i][e];
      o1[i]     = (short)tile[tc + 4 + i][e];
      o1[4 + i] = (short)tile[tc + 12 + i][e];
    }
    unsigned short* dst = VT + ((size_t)(bh * 64 + e)) * 2048 + tt * 64 + tc;
    *(bf16x8*)dst = o0;
    *(bf16x8*)(dst + 8) = o1;
  }
}

// ---------- flash attention: KVBLK=128, XCD-local KV, fixed-max softmax ----------
// grid 512; bid swizzle: all 8 qg-blocks of one (split,bh) share bid%8 -> same XCD L2.
// block 512 = 8 waves; wave = 32 Q-rows; P = 2^(S-15) exactly (|S_log2| <= 14.5).
// sum kept in 4 independent partials (shorter VALU dependency chain).
__global__ __launch_bounds__(512, 4) void attn_k(const unsigned short* __restrict__ Q,
                                                 const unsigned short* __restrict__ K,
                                                 const unsigned short* __restrict__ VT,
                                                 unsigned short* __restrict__ Opart,
                                                 float* __restrict__ ms) {
  __shared__ unsigned short Ks[2][128 * 64];   // [ktok][e],  granule ^= (row&7)
  __shared__ unsigned short Vs[2][64 * 128];   // [e][ktok'], granule low3 ^= (row&7)
  const float M0 = 15.0f;
  int tid = threadIdx.x;
  int w = tid >> 6, l = tid & 63;
  int q = l & 31, hi = l >> 5;
  int bid = blockIdx.x;
  int sbh = (bid >> 6) * 8 + (bid & 7);
  int qg = (bid >> 3) & 7;
  int split = sbh >> 5, bh = sbh & 31;
  int qrow0 = qg * 256 + w * 32;
  const unsigned short* Kbase = K + (size_t)bh * 2048 * 64 + (size_t)split * 1024 * 64;
  const unsigned short* Vbase = VT + (size_t)bh * 64 * 2048 + split * 1024;

  bf16x8 qa[4];
#pragma unroll
  for (int s = 0; s < 4; s++)
    qa[s] = *(const bf16x8*)(Q + ((size_t)bh * 2048 + qrow0 + q) * 64 + s * 16 + hi * 8);

  int koff0[4], koff1[4], voff0[4], voff1[4];
#pragma unroll
  for (int se = 0; se < 4; se++) {
    int gk = se * 2 + hi;
    koff0[se] = q * 64 + ((gk ^ (q & 7)) * 8);
    koff1[se] = (32 + q) * 64 + ((gk ^ (q & 7)) * 8);
    voff0[se] = q * 128 + ((gk ^ (q & 7)) * 8);
    voff1[se] = (32 + q) * 128 + ((gk ^ (q & 7)) * 8);
  }

  int slA = tid, slB = 512 + tid;
  int krA = slA >> 3, kgA = (slA & 7) ^ (krA & 7);
  int krB = slB >> 3, kgB = (slB & 7) ^ (krB & 7);
  int vrA = slA >> 4, vgA = (slA & 15) ^ (vrA & 7);
  int vrB = slB >> 4, vgB = (slB & 15) ^ (vrB & 7);
  const unsigned short* KgA = Kbase + (size_t)krA * 64 + kgA * 8;
  const unsigned short* KgB = Kbase + (size_t)krB * 64 + kgB * 8;
  const unsigned short* VgA = Vbase + (size_t)vrA * 2048 + vgA * 8;
  const unsigned short* VgB = Vbase + (size_t)vrB * 2048 + vgB * 8;

  f32x16 acc0, acc1, fz;
  for (int i = 0; i < 16; i++) { acc0[i] = 0.f; acc1[i] = 0.f; fz[i] = 0.f; }
  f32x4 sums;
  for (int i = 0; i < 4; i++) sums[i] = 0.f;

  auto stage = [&](int buf, int kt) {
    gload_lds16(KgA + (size_t)kt * 64, &Ks[buf][(w * 64) * 8]);
    gload_lds16(KgB + (size_t)kt * 64, &Ks[buf][(512 + w * 64) * 8]);
    gload_lds16(VgA + kt, &Vs[buf][(w * 64) * 8]);
    gload_lds16(VgB + kt, &Vs[buf][(512 + w * 64) * 8]);
  };

  stage(0, 0);
  __syncthreads();
  int cur = 0;
  for (int it = 0; it < 8; it++) {
    if (it < 7) stage(cur ^ 1, (it + 1) * 128);
    const unsigned short* Ksc = Ks[cur];
    const unsigned short* Vsc = Vs[cur];
#pragma unroll
    for (int ss = 0; ss < 2; ss++) {
      int kro = ss * 4096;
      int vco = ss * 64;
      bf16x8 ka0 = *(const bf16x8*)&Ksc[kro + koff0[0]];
      bf16x8 ka1 = *(const bf16x8*)&Ksc[kro + koff1[0]];
      __builtin_amdgcn_s_setprio(1);
      f32x16 s0 = __builtin_amdgcn_mfma_f32_32x32x16_bf16(ka0, qa[0], fz, 0, 0, 0);
      f32x16 s1 = __builtin_amdgcn_mfma_f32_32x32x16_bf16(ka1, qa[0], fz, 0, 0, 0);
#pragma unroll
      for (int se = 1; se < 4; se++) {
        ka0 = *(const bf16x8*)&Ksc[kro + koff0[se]];
        ka1 = *(const bf16x8*)&Ksc[kro + koff1[se]];
        s0 = __builtin_amdgcn_mfma_f32_32x32x16_bf16(ka0, qa[se], s0, 0, 0, 0);
        s1 = __builtin_amdgcn_mfma_f32_32x32x16_bf16(ka1, qa[se], s1, 0, 0, 0);
      }
      __builtin_amdgcn_s_setprio(0);

      bf16x8 pf[4];
#pragma unroll
      for (int n = 0; n < 4; n++) {
        int o = (n & 1) * 8;
        u32x4 t;
#pragma unroll
        for (int j = 0; j < 4; j++) {
          float a = (n < 2) ? s0[o + 2 * j] : s1[o + 2 * j];
          float b = (n < 2) ? s0[o + 2 * j + 1] : s1[o + 2 * j + 1];
          float e0 = exp2raw(a - M0);
          float e1 = exp2raw(b - M0);
          sums[n] += e0 + e1;          // 4 independent accumulation chains
          t[j] = cvtpk(e0, e1);
        }
        pf[n] = __builtin_bit_cast(bf16x8, t);
      }

      __builtin_amdgcn_s_setprio(1);
#pragma unroll
      for (int n = 0; n < 4; n++) {
        bf16x8 va0 = *(const bf16x8*)&Vsc[vco + voff0[n]];
        bf16x8 va1 = *(const bf16x8*)&Vsc[vco + voff1[n]];
        acc0 = __builtin_amdgcn_mfma_f32_32x32x16_bf16(va0, pf[n], acc0, 0, 0, 0);
        acc1 = __builtin_amdgcn_mfma_f32_32x32x16_bf16(va1, pf[n], acc1, 0, 0, 0);
      }
      __builtin_amdgcn_s_setprio(0);
    }
    __syncthreads();
    cur ^= 1;
  }

  float sum = (sums[0] + sums[1]) + (sums[2] + sums[3]);
  sum += __shfl_xor(sum, 32);
  size_t prow = (size_t)(split * 32 + bh) * 2048 + qrow0 + q;
  unsigned short* Op = Opart + prow * 64;
#pragma unroll
  for (int et = 0; et < 2; et++) {
    const f32x16& a = et ? acc1 : acc0;
#pragma unroll
    for (int qd = 0; qd < 4; qd++) {
      int e0 = et * 32 + 4 * hi + qd * 8;
      u32x2 t;
      t[0] = cvtpk(a[qd * 4 + 0], a[qd * 4 + 1]);
      t[1] = cvtpk(a[qd * 4 + 2], a[qd * 4 + 3]);
      *(bf16x4*)&Op[e0] = __builtin_bit_cast(bf16x4, t);
    }
  }
  if (hi == 0) ms[prow] = sum;
}

extern "C" void kernel_launch(void* const* d_in, const int* in_sizes, int n_in,
                              void* d_out, int out_size, void* d_ws, size_t ws_size,
                              hipStream_t stream) {
  const float* x      = (const float*)d_in[0];
  const float* pos    = (const float*)d_in[1];
  const float* cond   = (const float*)d_in[2];
  const float* norm_w = (const float*)d_in[3];
  const float* qkv_w  = (const float*)d_in[4];
  const float* out_w  = (const float*)d_in[5];
  const float* scale  = (const float*)d_in[6];
  const float* freqs  = (const float*)d_in[7];
  float* out = (float*)d_out;
  char* ws = (char*)d_ws;

  const size_t o_ada    = 0;
  const size_t o_rowsum = 8192;
  const size_t o_scales = 24576;
  const size_t o_ascale = 24832;
  const size_t o_oscale = 41216;
  const size_t o_Wq8    = 57600;
  const size_t o_Wo8    = o_Wq8 + 3145728;
  const size_t o_AqQ    = o_Wo8 + 1048576;
  const size_t o_qkv    = o_AqQ + 8388608;
  const size_t o_K      = o_qkv + 25165824;
  const size_t o_VT     = o_K + 8388608;

  float* ada            = (float*)(ws + o_ada);
  float* rowsum         = (float*)(ws + o_rowsum);
  float* scales         = (float*)(ws + o_scales);
  float* ascale         = (float*)(ws + o_ascale);
  float* oscale         = (float*)(ws + o_oscale);
  signed char* Wq8      = (signed char*)(ws + o_Wq8);
  signed char* Wo8      = (signed char*)(ws + o_Wo8);
  signed char* Aq8      = (signed char*)(ws + o_AqQ);
  unsigned short* Qb    = (unsigned short*)(ws + o_AqQ);
  unsigned short* qkv   = (unsigned short*)(ws + o_qkv);
  unsigned short* Opart = (unsigned short*)(ws + o_qkv);
  float* msb            = (float*)(ws + o_qkv + 2ull*32*2048*64*2);
  unsigned short* Kb    = (unsigned short*)(ws + o_K);
  signed char* Oq8      = (signed char*)(ws + o_K);
  unsigned short* VT    = (unsigned short*)(ws + o_VT);

  wrada_k<<<4608, 256, 0, stream>>>(qkv_w, out_w, cond, norm_w, rowsum, ada);
  finalize_k<<<1, 256, 0, stream>>>(rowsum, scales);
  wqrms_k<<<8192, 256, 0, stream>>>(qkv_w, out_w, scales, x, ada, Wq8, Wo8, Aq8, ascale);
  gemm_i8<<<768, 256, 0, stream>>>(Aq8, Wq8, 3072, 1024, 768, 0, ascale, &scales[0],
                                   nullptr, nullptr, qkv);
  prep_k<<<5120, 256, 0, stream>>>(qkv, pos, scale, freqs, Qb, Kb, VT);
  attn_k<<<512, 512, 0, stream>>>(Qb, Kb, VT, Opart, msb);
  oquant_k<<<4096, 256, 0, stream>>>(Opart, msb, Oq8, oscale);
  gemm_i8<<<256, 256, 0, stream>>>(Oq8, Wo8, 1024, 1024, 256, 1, oscale, &scales[2],
                                   x, out, nullptr);
}

// Round 19
// 141.313 us; speedup vs baseline: 1.1746x; 1.1746x over previous
//
#include <hip/hip_runtime.h>
#include <hip/hip_bf16.h>
#include <math.h>

typedef __attribute__((ext_vector_type(8))) short bf16x8;
typedef __attribute__((ext_vector_type(4))) short bf16x4;
typedef __attribute__((ext_vector_type(4))) float f32x4;
typedef __attribute__((ext_vector_type(16))) float f32x16;
typedef __attribute__((ext_vector_type(4))) unsigned u32x4;
typedef __attribute__((ext_vector_type(2))) unsigned u32x2;
typedef __attribute__((ext_vector_type(4))) int i32x4;

#define DEV static __device__ __forceinline__
#define LOG2E 1.4426950408889634f
#define INV2PI 0.15915494309189535f

DEV unsigned short f2bf(float f) {
  unsigned int u = __float_as_uint(f);
  u += 0x7FFFu + ((u >> 16) & 1u);   // RNE, inputs finite
  return (unsigned short)(u >> 16);
}
DEV float bf2f(unsigned short h) { return __uint_as_float(((unsigned int)h) << 16); }
DEV unsigned cvtpk(float lo, float hi) {
  unsigned r;
  asm("v_cvt_pk_bf16_f32 %0, %1, %2" : "=v"(r) : "v"(lo), "v"(hi));
  return r;
}
DEV float exp2raw(float x) {            // inputs in [-30,0]: no fixup needed
  float r;
  asm("v_exp_f32 %0, %1" : "=v"(r) : "v"(x));
  return r;
}
DEV float fract_raw(float x) { float r; asm("v_fract_f32 %0, %1" : "=v"(r) : "v"(x)); return r; }
DEV float sin_rev(float x)   { float r; asm("v_sin_f32 %0, %1"   : "=v"(r) : "v"(x)); return r; }
DEV float cos_rev(float x)   { float r; asm("v_cos_f32 %0, %1"   : "=v"(r) : "v"(x)); return r; }
DEV float wsum(float v) { for (int o = 32; o; o >>= 1) v += __shfl_xor(v, o); return v; }
DEV float wmaxr(float v) { for (int o = 32; o; o >>= 1) v = fmaxf(v, __shfl_xor(v, o)); return v; }

// async global->LDS, 16B per lane; dest = wave-uniform base + lane*16
DEV void gload_lds16(const void* g, void* s) {
  __builtin_amdgcn_global_load_lds(
      (const __attribute__((address_space(1))) unsigned int*)g,
      (__attribute__((address_space(3))) unsigned int*)s, 16, 0, 0);
}

// ---------- k1: blocks [0,4096) per-row |w| sums; [4096,4608) ada ----------
__global__ __launch_bounds__(256) void wrada_k(const float* __restrict__ qw,
                                               const float* __restrict__ ow,
                                               const float* __restrict__ cond,
                                               const float* __restrict__ nw,
                                               float* __restrict__ rowsum,
                                               float* __restrict__ ada) {
  if (blockIdx.x < 4096) {
    int row = blockIdx.x;  // 0..3071 -> qkv_w, 3072..4095 -> out_w
    const float* p = (row < 3072) ? (qw + (size_t)row * 1024)
                                  : (ow + (size_t)(row - 3072) * 1024);
    f32x4 v = *(const f32x4*)&p[threadIdx.x * 4];
    float s = fabsf(v[0]) + fabsf(v[1]) + fabsf(v[2]) + fabsf(v[3]);
    s = wsum(s);
    __shared__ float sh[4];
    if ((threadIdx.x & 63) == 0) sh[threadIdx.x >> 6] = s;
    __syncthreads();
    if (threadIdx.x == 0) rowsum[row] = sh[0] + sh[1] + sh[2] + sh[3];
  } else {
    int bid2 = blockIdx.x - 4096;          // 0..511
    int b = bid2 >> 8;
    int j = (bid2 & 255) * 4 + (threadIdx.x >> 6);
    int l = threadIdx.x & 63;
    const float* cp = cond + b * 1024;
    const float* wp = nw + (size_t)j * 1024;
    float s = 0.f;
    for (int c = l; c < 1024; c += 64) s += cp[c] * wp[c];
    s = wsum(s);
    if (l == 0) ada[b * 1024 + j] = 1.f + s;
  }
}

__global__ __launch_bounds__(256) void finalize_k(const float* __restrict__ rowsum,
                                                  float* __restrict__ scales) {
  float s1 = 0.f, s2 = 0.f;
  for (int i = threadIdx.x; i < 3072; i += 256) s1 += rowsum[i];
  for (int i = threadIdx.x; i < 1024; i += 256) s2 += rowsum[3072 + i];
  s1 = wsum(s1); s2 = wsum(s2);
  __shared__ float sh1[4], sh2[4];
  if ((threadIdx.x & 63) == 0) { sh1[threadIdx.x >> 6] = s1; sh2[threadIdx.x >> 6] = s2; }
  __syncthreads();
  if (threadIdx.x == 0) {
    float m1 = fmaxf((sh1[0] + sh1[1] + sh1[2] + sh1[3]) / (3072.f * 1024.f), 1e-5f);
    float m2 = fmaxf((sh2[0] + sh2[1] + sh2[2] + sh2[3]) / (1024.f * 1024.f), 1e-5f);
    scales[0] = m1; scales[1] = 1.f / m1;   // qkv_w: mean, 1/mean
    scales[2] = m2; scales[3] = 1.f / m2;   // out_w
  }
}

// ---------- k2: blocks [0,4096) ternary wquant -> i8; [4096,8192) RMSNorm+act_quant ----------
__global__ __launch_bounds__(256) void wqrms_k(const float* __restrict__ qw,
                                               const float* __restrict__ ow,
                                               const float* __restrict__ scales,
                                               const float* __restrict__ x,
                                               const float* __restrict__ ada,
                                               signed char* __restrict__ Wq,
                                               signed char* __restrict__ Wo,
                                               signed char* __restrict__ Aq,
                                               float* __restrict__ ascale) {
  if (blockIdx.x < 4096) {
    int i0 = (blockIdx.x * 256 + threadIdx.x) * 4;
    if (i0 < 3072 * 1024) {
      f32x4 v = *(const f32x4*)&qw[i0];
      unsigned pk = 0;
      for (int j = 0; j < 4; j++) {
        int t = (int)fminf(fmaxf(rintf(v[j] * scales[1]), -1.f), 1.f);
        pk |= ((unsigned)t & 0xFFu) << (8 * j);
      }
      *(unsigned*)&Wq[i0] = pk;
    } else {
      int k = i0 - 3072 * 1024;
      f32x4 v = *(const f32x4*)&ow[k];
      unsigned pk = 0;
      for (int j = 0; j < 4; j++) {
        int t = (int)fminf(fmaxf(rintf(v[j] * scales[3]), -1.f), 1.f);
        pk |= ((unsigned)t & 0xFFu) << (8 * j);
      }
      *(unsigned*)&Wo[k] = pk;
    }
  } else {
    int row = blockIdx.x - 4096;   // b*2048 + t
    int b = row >> 11;
    const float* xr = x + (size_t)row * 1024;
    const float* ar = ada + b * 1024;
    int t4 = threadIdx.x * 4;
    f32x4 v = *(const f32x4*)&xr[t4];
    float ss = v[0]*v[0] + v[1]*v[1] + v[2]*v[2] + v[3]*v[3];
    ss = wsum(ss);
    __shared__ float sh[4], sh2[4];
    if ((threadIdx.x & 63) == 0) sh[threadIdx.x >> 6] = ss;
    __syncthreads();
    float inv = rsqrtf((sh[0] + sh[1] + sh[2] + sh[3]) * (1.f / 1024.f) + 1e-6f);
    f32x4 a = *(const f32x4*)&ar[t4];
    float xn[4]; float mx = 0.f;
    for (int i = 0; i < 4; i++) { xn[i] = v[i] * a[i] * inv; mx = fmaxf(mx, fabsf(xn[i])); }
    mx = wmaxr(mx);
    if ((threadIdx.x & 63) == 0) sh2[threadIdx.x >> 6] = mx;
    __syncthreads();
    float rmax = fmaxf(fmaxf(sh2[0], sh2[1]), fmaxf(sh2[2], sh2[3]));
    float s = 127.f / fmaxf(rmax, 1e-5f);
    unsigned pk = 0;
    for (int i = 0; i < 4; i++) {
      int ai = (int)fminf(fmaxf(rintf(xn[i] * s), -128.f), 127.f);
      pk |= ((unsigned)ai & 0xFFu) << (8 * i);
    }
    *(unsigned*)&Aq[(size_t)row * 1024 + t4] = pk;
    if (threadIdx.x == 0) ascale[row] = 1.f / s;
  }
}

// ---------- combine split-K partials + act_quant -> int8 ----------
__global__ __launch_bounds__(256) void oquant_k(const unsigned short* __restrict__ Opart,
                                                const float* __restrict__ ms,
                                                signed char* __restrict__ Oq,
                                                float* __restrict__ oscale) {
  int row = blockIdx.x;            // b*2048 + t
  int b = row >> 11, qrow = row & 2047;
  int t4 = threadIdx.x * 4;
  int h = t4 >> 6, e0 = t4 & 63;
  int bh = b * 16 + h;
  size_t i0 = (size_t)bh * 2048 + qrow;             // split 0
  size_t i1 = (size_t)(32 + bh) * 2048 + qrow;      // split 1
  float w = 1.f / (ms[i0] + ms[i1]);                // common 2^-15 factor cancels
  bf16x4 o0 = *(const bf16x4*)&Opart[i0 * 64 + e0];
  bf16x4 o1 = *(const bf16x4*)&Opart[i1 * 64 + e0];
  float v[4]; float mx = 0.f;
  for (int i = 0; i < 4; i++) {
    v[i] = (bf2f((unsigned short)o0[i]) + bf2f((unsigned short)o1[i])) * w;
    mx = fmaxf(mx, fabsf(v[i]));
  }
  mx = wmaxr(mx);
  __shared__ float sh[4];
  if ((threadIdx.x & 63) == 0) sh[threadIdx.x >> 6] = mx;
  __syncthreads();
  float rmax = fmaxf(fmaxf(sh[0], sh[1]), fmaxf(sh[2], sh[3]));
  float s = 127.f / fmaxf(rmax, 1e-5f);
  float is = 1.f / s;
  unsigned pk = 0;
  for (int i = 0; i < 4; i++) {
    int ai = (int)fminf(fmaxf(rintf(v[i] * s), -128.f), 127.f);
    pk |= ((unsigned)ai & 0xFFu) << (8 * i);
  }
  *(unsigned*)&Oq[(size_t)row * 1024 + t4] = pk;
  if (threadIdx.x == 0) oscale[row] = is;
}

// ---------- i8 GEMM: double-buffered LDS, ONE barrier per K-iter ----------
// C[M][N] = (A8 . B8^T) * rowsc[row] * wsc; 128x128 tile, BK=64, i32-exact accum.
__global__ __launch_bounds__(256, 3) void gemm_i8(const signed char* __restrict__ A8,
                                                  const signed char* __restrict__ B8,
                                                  int N, int K, int nwg, int mode,
                                                  const float* __restrict__ rowsc,
                                                  const float* __restrict__ wscp,
                                                  const float* __restrict__ skip,
                                                  float* __restrict__ outF,
                                                  unsigned short* __restrict__ outB) {
  __shared__ signed char As[2][128 * 64];
  __shared__ signed char Bs[2][128 * 64];
  int bid = blockIdx.x;
  int wg = (bid % 8) * (nwg >> 3) + (bid >> 3);   // XCD-chunked remap
  int bx = wg & 31, by = wg >> 5;                 // M=4096 -> 32 M-tiles
  int tid = threadIdx.x;
  int w = tid >> 6, l = tid & 63;
  int q = l & 15, g = l >> 4;
  int tm = bx * 128, tn = by * 128;
  int wr = w >> 1, wc = w & 1;
  float wsc = wscp[0];
  i32x4 acc[4][4];
  i32x4 zero = {0, 0, 0, 0};
#pragma unroll
  for (int m = 0; m < 4; m++)
#pragma unroll
    for (int n = 0; n < 4; n++) acc[m][n] = zero;
  int s0 = w * 64 + l, s1 = 256 + s0;
  int r0 = s0 >> 2, p0 = s0 & 3, gs0 = p0 ^ ((r0 >> 1) & 3);
  int r1 = s1 >> 2, p1 = s1 & 3, gs1 = p1 ^ ((r1 >> 1) & 3);
  const signed char* Ag0 = A8 + (size_t)(tm + r0) * K + gs0 * 16;
  const signed char* Ag1 = A8 + (size_t)(tm + r1) * K + gs1 * 16;
  const signed char* Bg0 = B8 + (size_t)(tn + r0) * K + gs0 * 16;
  const signed char* Bg1 = B8 + (size_t)(tn + r1) * K + gs1 * 16;
  int posq = ((q >> 1) & 3);

  auto stage = [&](int buf, int k0) {
    gload_lds16(Ag0 + k0, &As[buf][w * 1024]);
    gload_lds16(Ag1 + k0, &As[buf][4096 + w * 1024]);
    gload_lds16(Bg0 + k0, &Bs[buf][w * 1024]);
    gload_lds16(Bg1 + k0, &Bs[buf][4096 + w * 1024]);
  };

  stage(0, 0);
  __syncthreads();
  int cur = 0;
  for (int k0 = 0; k0 < K; k0 += 64) {
    if (k0 + 64 < K) stage(cur ^ 1, k0 + 64);     // prefetch overlaps MFMA
    int pg = (g ^ posq) * 16;
    i32x4 af[4], bfr[4];
#pragma unroll
    for (int m = 0; m < 4; m++)
      af[m] = *(const i32x4*)&As[cur][(wr * 64 + m * 16 + q) * 64 + pg];
#pragma unroll
    for (int n = 0; n < 4; n++)
      bfr[n] = *(const i32x4*)&Bs[cur][(wc * 64 + n * 16 + q) * 64 + pg];
#pragma unroll
    for (int m = 0; m < 4; m++)
#pragma unroll
      for (int n = 0; n < 4; n++)
        acc[m][n] = __builtin_amdgcn_mfma_i32_16x16x64_i8(af[m], bfr[n], acc[m][n], 0, 0, 0);
    __syncthreads();      // all waves done reading cur; prefetch vmcnt drained
    cur ^= 1;
  }
#pragma unroll
  for (int m = 0; m < 4; m++) {
#pragma unroll
    for (int r = 0; r < 4; r++) {
      int row = tm + wr * 64 + m * 16 + g * 4 + r;
      float dq = rowsc[row] * wsc;
#pragma unroll
      for (int n = 0; n < 4; n++) {
        int col = tn + wc * 64 + n * 16 + q;
        float vv = (float)acc[m][n][r] * dq;
        if (mode == 0) outB[(size_t)row * N + col] = f2bf(vv);
        else { size_t idx = (size_t)row * N + col; outF[idx] = vv + skip[idx]; }
      }
    }
  }
}

// ---------- fused prep v2: blocks [0,4096) = qk-norm+RoPE (vectorized bf16x8);
//                          [4096,5120) = V transpose ----------
__global__ __launch_bounds__(256) void prep_k(const unsigned short* __restrict__ qkv,
                                              const float* __restrict__ pos,
                                              const float* __restrict__ scale,
                                              const float* __restrict__ freqs,
                                              unsigned short* __restrict__ Qo,
                                              unsigned short* __restrict__ Ko,
                                              unsigned short* __restrict__ VT) {
  __shared__ unsigned short tile[64][72];
  int tid = threadIdx.x;
  if (blockIdx.x < 4096) {
    int t = blockIdx.x & 2047, b = blockIdx.x >> 11;
    int half = tid >> 7;            // 0 = Q, 1 = K
    int i = tid & 127;
    int h = i >> 3, j = i & 7;      // head, 8-elem slot (e = j*8..j*8+7)
    int lane = tid & 63;
    const unsigned short* src =
        qkv + ((size_t)(b * 2048 + t)) * 3072 + half * 1024 + h * 64 + j * 8;
    bf16x8 vv = *(const bf16x8*)src;
    float f[8]; float ss = 0.f;
#pragma unroll
    for (int m = 0; m < 8; m++) { f[m] = bf2f((unsigned short)vv[m]); ss += f[m] * f[m]; }
    ss += __shfl_xor(ss, 1);
    ss += __shfl_xor(ss, 2);
    ss += __shfl_xor(ss, 4);        // full-head sum (8 lanes x 8 elems)
    float fac = sqrtf(scale[h]) * rsqrtf(ss + 1e-6f);
#pragma unroll
    for (int m = 0; m < 8; m++) f[m] *= fac;
    // partner exchange: e<24 -> e+24 (lane+3), 24<=e<48 -> e-24 (lane-3)
    int plane = (j < 3) ? lane + 3 : ((j < 6) ? lane - 3 : lane);
    float p[8];
#pragma unroll
    for (int m = 0; m < 8; m++) p[m] = __shfl(f[m], plane);
    float outv[8];
    if (j < 6) {
      int a = (j < 3) ? j : j - 3;
      float sgn = (j < 3) ? -1.f : 1.f;
      float pth = pos[((size_t)(b * 2048 + t)) * 3 + a];
      f32x4 fr0 = *(const f32x4*)&freqs[h * 8];
      f32x4 fr1 = *(const f32x4*)&freqs[h * 8 + 4];
#pragma unroll
      for (int m = 0; m < 8; m++) {
        float frq = (m < 4) ? fr0[m] : fr1[m - 4];
        float rev = fract_raw(pth * frq * INV2PI);   // sin(2*pi*rev) == sin(th)
        float sn = sin_rev(rev), cs = cos_rev(rev);
        outv[m] = f[m] * cs + sgn * p[m] * sn;
      }
    } else {
#pragma unroll
      for (int m = 0; m < 8; m++) outv[m] = f[m];
    }
    bf16x8 o;
    size_t oi = ((size_t)((b * 16 + h) * 2048 + t)) * 64 + j * 8;
    if (half == 0) {
#pragma unroll
      for (int m = 0; m < 8; m++) o[m] = (short)f2bf(outv[m] * LOG2E);  // exp2-softmax prescale
      *(bf16x8*)(Qo + oi) = o;
    } else {
#pragma unroll
      for (int m = 0; m < 8; m++) o[m] = (short)f2bf(outv[m]);
      *(bf16x8*)(Ko + oi) = o;
    }
  } else {
    // V transpose: VT[b][h][e][t'], t' = bits2<->3 swap (bakes PV k-perm)
    int bid2 = blockIdx.x - 4096;
    int tt = bid2 & 31, bh = bid2 >> 5;
    int b = bh >> 4, h = bh & 15;
    for (int ro = 0; ro < 2; ro++) {
      int r = ro * 32 + (tid >> 3);
      int c = (tid & 7) * 8;
      *(bf16x8*)&tile[r][c] =
          *(const bf16x8*)(qkv + ((size_t)(b * 2048 + tt * 64 + r)) * 3072 + 2048 + h * 64 + c);
    }
    __syncthreads();
    int e = tid >> 2;
    int tc = (tid & 3) * 16;
    bf16x8 o0, o1;
#pragma unroll
    for (int i = 0; i < 4; i++) {
      o0[i]     = (short)tile[tc + i][e];
      o0[4 + i] = (short)tile[tc + 8 + i][e];
      o1[i]     = (short)tile[tc + 4 + i][e];
      o1[4 + i] = (short)tile[tc + 12 + i][e];
    }
    unsigned short* dst = VT + ((size_t)(bh * 64 + e)) * 2048 + tt * 64 + tc;
    *(bf16x8*)dst = o0;
    *(bf16x8*)(dst + 8) = o1;
  }
}

// ---------- flash attention (R17 form, scalar sum): KVBLK=128, XCD-local KV ----------
// grid 512; bid swizzle: all 8 qg-blocks of one (split,bh) share bid%8 -> same XCD L2.
// block 512 = 8 waves; wave = 32 Q-rows; P = 2^(S-15) exactly (|S_log2| <= 14.5).
__global__ __launch_bounds__(512, 4) void attn_k(const unsigned short* __restrict__ Q,
                                                 const unsigned short* __restrict__ K,
                                                 const unsigned short* __restrict__ VT,
                                                 unsigned short* __restrict__ Opart,
                                                 float* __restrict__ ms) {
  __shared__ unsigned short Ks[2][128 * 64];   // [ktok][e],  granule ^= (row&7)
  __shared__ unsigned short Vs[2][64 * 128];   // [e][ktok'], granule low3 ^= (row&7)
  const float M0 = 15.0f;
  int tid = threadIdx.x;
  int w = tid >> 6, l = tid & 63;
  int q = l & 31, hi = l >> 5;
  int bid = blockIdx.x;
  int sbh = (bid >> 6) * 8 + (bid & 7);
  int qg = (bid >> 3) & 7;
  int split = sbh >> 5, bh = sbh & 31;
  int qrow0 = qg * 256 + w * 32;
  const unsigned short* Kbase = K + (size_t)bh * 2048 * 64 + (size_t)split * 1024 * 64;
  const unsigned short* Vbase = VT + (size_t)bh * 64 * 2048 + split * 1024;

  bf16x8 qa[4];
#pragma unroll
  for (int s = 0; s < 4; s++)
    qa[s] = *(const bf16x8*)(Q + ((size_t)bh * 2048 + qrow0 + q) * 64 + s * 16 + hi * 8);

  int koff0[4], koff1[4], voff0[4], voff1[4];
#pragma unroll
  for (int se = 0; se < 4; se++) {
    int gk = se * 2 + hi;
    koff0[se] = q * 64 + ((gk ^ (q & 7)) * 8);
    koff1[se] = (32 + q) * 64 + ((gk ^ (q & 7)) * 8);
    voff0[se] = q * 128 + ((gk ^ (q & 7)) * 8);
    voff1[se] = (32 + q) * 128 + ((gk ^ (q & 7)) * 8);
  }

  int slA = tid, slB = 512 + tid;
  int krA = slA >> 3, kgA = (slA & 7) ^ (krA & 7);
  int krB = slB >> 3, kgB = (slB & 7) ^ (krB & 7);
  int vrA = slA >> 4, vgA = (slA & 15) ^ (vrA & 7);
  int vrB = slB >> 4, vgB = (slB & 15) ^ (vrB & 7);
  const unsigned short* KgA = Kbase + (size_t)krA * 64 + kgA * 8;
  const unsigned short* KgB = Kbase + (size_t)krB * 64 + kgB * 8;
  const unsigned short* VgA = Vbase + (size_t)vrA * 2048 + vgA * 8;
  const unsigned short* VgB = Vbase + (size_t)vrB * 2048 + vgB * 8;

  f32x16 acc0, acc1, fz;
  for (int i = 0; i < 16; i++) { acc0[i] = 0.f; acc1[i] = 0.f; fz[i] = 0.f; }
  float sum = 0.f;

  auto stage = [&](int buf, int kt) {
    gload_lds16(KgA + (size_t)kt * 64, &Ks[buf][(w * 64) * 8]);
    gload_lds16(KgB + (size_t)kt * 64, &Ks[buf][(512 + w * 64) * 8]);
    gload_lds16(VgA + kt, &Vs[buf][(w * 64) * 8]);
    gload_lds16(VgB + kt, &Vs[buf][(512 + w * 64) * 8]);
  };

  stage(0, 0);
  __syncthreads();
  int cur = 0;
  for (int it = 0; it < 8; it++) {
    if (it < 7) stage(cur ^ 1, (it + 1) * 128);
    const unsigned short* Ksc = Ks[cur];
    const unsigned short* Vsc = Vs[cur];
#pragma unroll
    for (int ss = 0; ss < 2; ss++) {
      int kro = ss * 4096;
      int vco = ss * 64;
      bf16x8 ka0 = *(const bf16x8*)&Ksc[kro + koff0[0]];
      bf16x8 ka1 = *(const bf16x8*)&Ksc[kro + koff1[0]];
      __builtin_amdgcn_s_setprio(1);
      f32x16 s0 = __builtin_amdgcn_mfma_f32_32x32x16_bf16(ka0, qa[0], fz, 0, 0, 0);
      f32x16 s1 = __builtin_amdgcn_mfma_f32_32x32x16_bf16(ka1, qa[0], fz, 0, 0, 0);
#pragma unroll
      for (int se = 1; se < 4; se++) {
        ka0 = *(const bf16x8*)&Ksc[kro + koff0[se]];
        ka1 = *(const bf16x8*)&Ksc[kro + koff1[se]];
        s0 = __builtin_amdgcn_mfma_f32_32x32x16_bf16(ka0, qa[se], s0, 0, 0, 0);
        s1 = __builtin_amdgcn_mfma_f32_32x32x16_bf16(ka1, qa[se], s1, 0, 0, 0);
      }
      __builtin_amdgcn_s_setprio(0);

      bf16x8 pf[4];
#pragma unroll
      for (int n = 0; n < 4; n++) {
        int o = (n & 1) * 8;
        u32x4 t;
#pragma unroll
        for (int j = 0; j < 4; j++) {
          float a = (n < 2) ? s0[o + 2 * j] : s1[o + 2 * j];
          float b = (n < 2) ? s0[o + 2 * j + 1] : s1[o + 2 * j + 1];
          float e0 = exp2raw(a - M0);
          float e1 = exp2raw(b - M0);
          sum += e0 + e1;
          t[j] = cvtpk(e0, e1);
        }
        pf[n] = __builtin_bit_cast(bf16x8, t);
      }

      __builtin_amdgcn_s_setprio(1);
#pragma unroll
      for (int n = 0; n < 4; n++) {
        bf16x8 va0 = *(const bf16x8*)&Vsc[vco + voff0[n]];
        bf16x8 va1 = *(const bf16x8*)&Vsc[vco + voff1[n]];
        acc0 = __builtin_amdgcn_mfma_f32_32x32x16_bf16(va0, pf[n], acc0, 0, 0, 0);
        acc1 = __builtin_amdgcn_mfma_f32_32x32x16_bf16(va1, pf[n], acc1, 0, 0, 0);
      }
      __builtin_amdgcn_s_setprio(0);
    }
    __syncthreads();
    cur ^= 1;
  }

  sum += __shfl_xor(sum, 32);
  size_t prow = (size_t)(split * 32 + bh) * 2048 + qrow0 + q;
  unsigned short* Op = Opart + prow * 64;
#pragma unroll
  for (int et = 0; et < 2; et++) {
    const f32x16& a = et ? acc1 : acc0;
#pragma unroll
    for (int qd = 0; qd < 4; qd++) {
      int e0 = et * 32 + 4 * hi + qd * 8;
      u32x2 t;
      t[0] = cvtpk(a[qd * 4 + 0], a[qd * 4 + 1]);
      t[1] = cvtpk(a[qd * 4 + 2], a[qd * 4 + 3]);
      *(bf16x4*)&Op[e0] = __builtin_bit_cast(bf16x4, t);
    }
  }
  if (hi == 0) ms[prow] = sum;
}

extern "C" void kernel_launch(void* const* d_in, const int* in_sizes, int n_in,
                              void* d_out, int out_size, void* d_ws, size_t ws_size,
                              hipStream_t stream) {
  const float* x      = (const float*)d_in[0];
  const float* pos    = (const float*)d_in[1];
  const float* cond   = (const float*)d_in[2];
  const float* norm_w = (const float*)d_in[3];
  const float* qkv_w  = (const float*)d_in[4];
  const float* out_w  = (const float*)d_in[5];
  const float* scale  = (const float*)d_in[6];
  const float* freqs  = (const float*)d_in[7];
  float* out = (float*)d_out;
  char* ws = (char*)d_ws;

  const size_t o_ada    = 0;
  const size_t o_rowsum = 8192;
  const size_t o_scales = 24576;
  const size_t o_ascale = 24832;
  const size_t o_oscale = 41216;
  const size_t o_Wq8    = 57600;
  const size_t o_Wo8    = o_Wq8 + 3145728;
  const size_t o_AqQ    = o_Wo8 + 1048576;
  const size_t o_qkv    = o_AqQ + 8388608;
  const size_t o_K      = o_qkv + 25165824;
  const size_t o_VT     = o_K + 8388608;

  float* ada            = (float*)(ws + o_ada);
  float* rowsum         = (float*)(ws + o_rowsum);
  float* scales         = (float*)(ws + o_scales);
  float* ascale         = (float*)(ws + o_ascale);
  float* oscale         = (float*)(ws + o_oscale);
  signed char* Wq8      = (signed char*)(ws + o_Wq8);
  signed char* Wo8      = (signed char*)(ws + o_Wo8);
  signed char* Aq8      = (signed char*)(ws + o_AqQ);
  unsigned short* Qb    = (unsigned short*)(ws + o_AqQ);
  unsigned short* qkv   = (unsigned short*)(ws + o_qkv);
  unsigned short* Opart = (unsigned short*)(ws + o_qkv);
  float* msb            = (float*)(ws + o_qkv + 2ull*32*2048*64*2);
  unsigned short* Kb    = (unsigned short*)(ws + o_K);
  signed char* Oq8      = (signed char*)(ws + o_K);
  unsigned short* VT    = (unsigned short*)(ws + o_VT);

  wrada_k<<<4608, 256, 0, stream>>>(qkv_w, out_w, cond, norm_w, rowsum, ada);
  finalize_k<<<1, 256, 0, stream>>>(rowsum, scales);
  wqrms_k<<<8192, 256, 0, stream>>>(qkv_w, out_w, scales, x, ada, Wq8, Wo8, Aq8, ascale);
  gemm_i8<<<768, 256, 0, stream>>>(Aq8, Wq8, 3072, 1024, 768, 0, ascale, &scales[0],
                                   nullptr, nullptr, qkv);
  prep_k<<<5120, 256, 0, stream>>>(qkv, pos, scale, freqs, Qb, Kb, VT);
  attn_k<<<512, 512, 0, stream>>>(Qb, Kb, VT, Opart, msb);
  oquant_k<<<4096, 256, 0, stream>>>(Opart, msb, Oq8, oscale);
  gemm_i8<<<256, 256, 0, stream>>>(Oq8, Wo8, 1024, 1024, 256, 1, oscale, &scales[2],
                                   x, out, nullptr);
}

// Round 20
// 134.355 us; speedup vs baseline: 1.2355x; 1.0518x over previous
//
#include <hip/hip_runtime.h>
#include <hip/hip_bf16.h>
#include <math.h>

typedef __attribute__((ext_vector_type(8))) short bf16x8;
typedef __attribute__((ext_vector_type(4))) short bf16x4;
typedef __attribute__((ext_vector_type(4))) float f32x4;
typedef __attribute__((ext_vector_type(16))) float f32x16;
typedef __attribute__((ext_vector_type(4))) unsigned u32x4;
typedef __attribute__((ext_vector_type(2))) unsigned u32x2;
typedef __attribute__((ext_vector_type(4))) int i32x4;

#define DEV static __device__ __forceinline__
#define LOG2E 1.4426950408889634f
#define INV2PI 0.15915494309189535f

DEV unsigned short f2bf(float f) {
  unsigned int u = __float_as_uint(f);
  u += 0x7FFFu + ((u >> 16) & 1u);   // RNE, inputs finite
  return (unsigned short)(u >> 16);
}
DEV float bf2f(unsigned short h) { return __uint_as_float(((unsigned int)h) << 16); }
DEV unsigned cvtpk(float lo, float hi) {
  unsigned r;
  asm("v_cvt_pk_bf16_f32 %0, %1, %2" : "=v"(r) : "v"(lo), "v"(hi));
  return r;
}
DEV float exp2raw(float x) {            // inputs in [-30,0]: no fixup needed
  float r;
  asm("v_exp_f32 %0, %1" : "=v"(r) : "v"(x));
  return r;
}
DEV float fract_raw(float x) { float r; asm("v_fract_f32 %0, %1" : "=v"(r) : "v"(x)); return r; }
DEV float sin_rev(float x)   { float r; asm("v_sin_f32 %0, %1"   : "=v"(r) : "v"(x)); return r; }
DEV float cos_rev(float x)   { float r; asm("v_cos_f32 %0, %1"   : "=v"(r) : "v"(x)); return r; }
DEV float wsum(float v) { for (int o = 32; o; o >>= 1) v += __shfl_xor(v, o); return v; }
DEV float wmaxr(float v) { for (int o = 32; o; o >>= 1) v = fmaxf(v, __shfl_xor(v, o)); return v; }

// async global->LDS, 16B per lane; dest = wave-uniform base + lane*16
DEV void gload_lds16(const void* g, void* s) {
  __builtin_amdgcn_global_load_lds(
      (const __attribute__((address_space(1))) unsigned int*)g,
      (__attribute__((address_space(3))) unsigned int*)s, 16, 0, 0);
}

// ---------- k1: blocks [0,4096) per-row |w| sums; [4096,4608) ada ----------
__global__ __launch_bounds__(256) void wrada_k(const float* __restrict__ qw,
                                               const float* __restrict__ ow,
                                               const float* __restrict__ cond,
                                               const float* __restrict__ nw,
                                               float* __restrict__ rowsum,
                                               float* __restrict__ ada) {
  if (blockIdx.x < 4096) {
    int row = blockIdx.x;  // 0..3071 -> qkv_w, 3072..4095 -> out_w
    const float* p = (row < 3072) ? (qw + (size_t)row * 1024)
                                  : (ow + (size_t)(row - 3072) * 1024);
    f32x4 v = *(const f32x4*)&p[threadIdx.x * 4];
    float s = fabsf(v[0]) + fabsf(v[1]) + fabsf(v[2]) + fabsf(v[3]);
    s = wsum(s);
    __shared__ float sh[4];
    if ((threadIdx.x & 63) == 0) sh[threadIdx.x >> 6] = s;
    __syncthreads();
    if (threadIdx.x == 0) rowsum[row] = sh[0] + sh[1] + sh[2] + sh[3];
  } else {
    int bid2 = blockIdx.x - 4096;          // 0..511
    int b = bid2 >> 8;
    int j = (bid2 & 255) * 4 + (threadIdx.x >> 6);
    int l = threadIdx.x & 63;
    const float* cp = cond + b * 1024;
    const float* wp = nw + (size_t)j * 1024;
    float s = 0.f;
    for (int c = l; c < 1024; c += 64) s += cp[c] * wp[c];
    s = wsum(s);
    if (l == 0) ada[b * 1024 + j] = 1.f + s;
  }
}

__global__ __launch_bounds__(256) void finalize_k(const float* __restrict__ rowsum,
                                                  float* __restrict__ scales) {
  float s1 = 0.f, s2 = 0.f;
  for (int i = threadIdx.x; i < 3072; i += 256) s1 += rowsum[i];
  for (int i = threadIdx.x; i < 1024; i += 256) s2 += rowsum[3072 + i];
  s1 = wsum(s1); s2 = wsum(s2);
  __shared__ float sh1[4], sh2[4];
  if ((threadIdx.x & 63) == 0) { sh1[threadIdx.x >> 6] = s1; sh2[threadIdx.x >> 6] = s2; }
  __syncthreads();
  if (threadIdx.x == 0) {
    float m1 = fmaxf((sh1[0] + sh1[1] + sh1[2] + sh1[3]) / (3072.f * 1024.f), 1e-5f);
    float m2 = fmaxf((sh2[0] + sh2[1] + sh2[2] + sh2[3]) / (1024.f * 1024.f), 1e-5f);
    scales[0] = m1; scales[1] = 1.f / m1;   // qkv_w: mean, 1/mean
    scales[2] = m2; scales[3] = 1.f / m2;   // out_w
  }
}

// ---------- k2: blocks [0,4096) ternary wquant -> i8; [4096,8192) RMSNorm+act_quant ----------
__global__ __launch_bounds__(256) void wqrms_k(const float* __restrict__ qw,
                                               const float* __restrict__ ow,
                                               const float* __restrict__ scales,
                                               const float* __restrict__ x,
                                               const float* __restrict__ ada,
                                               signed char* __restrict__ Wq,
                                               signed char* __restrict__ Wo,
                                               signed char* __restrict__ Aq,
                                               float* __restrict__ ascale) {
  if (blockIdx.x < 4096) {
    int i0 = (blockIdx.x * 256 + threadIdx.x) * 4;
    if (i0 < 3072 * 1024) {
      f32x4 v = *(const f32x4*)&qw[i0];
      unsigned pk = 0;
      for (int j = 0; j < 4; j++) {
        int t = (int)fminf(fmaxf(rintf(v[j] * scales[1]), -1.f), 1.f);
        pk |= ((unsigned)t & 0xFFu) << (8 * j);
      }
      *(unsigned*)&Wq[i0] = pk;
    } else {
      int k = i0 - 3072 * 1024;
      f32x4 v = *(const f32x4*)&ow[k];
      unsigned pk = 0;
      for (int j = 0; j < 4; j++) {
        int t = (int)fminf(fmaxf(rintf(v[j] * scales[3]), -1.f), 1.f);
        pk |= ((unsigned)t & 0xFFu) << (8 * j);
      }
      *(unsigned*)&Wo[k] = pk;
    }
  } else {
    int row = blockIdx.x - 4096;   // b*2048 + t
    int b = row >> 11;
    const float* xr = x + (size_t)row * 1024;
    const float* ar = ada + b * 1024;
    int t4 = threadIdx.x * 4;
    f32x4 v = *(const f32x4*)&xr[t4];
    float ss = v[0]*v[0] + v[1]*v[1] + v[2]*v[2] + v[3]*v[3];
    ss = wsum(ss);
    __shared__ float sh[4], sh2[4];
    if ((threadIdx.x & 63) == 0) sh[threadIdx.x >> 6] = ss;
    __syncthreads();
    float inv = rsqrtf((sh[0] + sh[1] + sh[2] + sh[3]) * (1.f / 1024.f) + 1e-6f);
    f32x4 a = *(const f32x4*)&ar[t4];
    float xn[4]; float mx = 0.f;
    for (int i = 0; i < 4; i++) { xn[i] = v[i] * a[i] * inv; mx = fmaxf(mx, fabsf(xn[i])); }
    mx = wmaxr(mx);
    if ((threadIdx.x & 63) == 0) sh2[threadIdx.x >> 6] = mx;
    __syncthreads();
    float rmax = fmaxf(fmaxf(sh2[0], sh2[1]), fmaxf(sh2[2], sh2[3]));
    float s = 127.f / fmaxf(rmax, 1e-5f);
    unsigned pk = 0;
    for (int i = 0; i < 4; i++) {
      int ai = (int)fminf(fmaxf(rintf(xn[i] * s), -128.f), 127.f);
      pk |= ((unsigned)ai & 0xFFu) << (8 * i);
    }
    *(unsigned*)&Aq[(size_t)row * 1024 + t4] = pk;
    if (threadIdx.x == 0) ascale[row] = 1.f / s;
  }
}

// ---------- combine split-K partials + act_quant -> int8 ----------
__global__ __launch_bounds__(256) void oquant_k(const unsigned short* __restrict__ Opart,
                                                const float* __restrict__ ms,
                                                signed char* __restrict__ Oq,
                                                float* __restrict__ oscale) {
  int row = blockIdx.x;            // b*2048 + t
  int b = row >> 11, qrow = row & 2047;
  int t4 = threadIdx.x * 4;
  int h = t4 >> 6, e0 = t4 & 63;
  int bh = b * 16 + h;
  size_t i0 = (size_t)bh * 2048 + qrow;             // split 0
  size_t i1 = (size_t)(32 + bh) * 2048 + qrow;      // split 1
  float w = 1.f / (ms[i0] + ms[i1]);                // common 2^-15 factor cancels
  bf16x4 o0 = *(const bf16x4*)&Opart[i0 * 64 + e0];
  bf16x4 o1 = *(const bf16x4*)&Opart[i1 * 64 + e0];
  float v[4]; float mx = 0.f;
  for (int i = 0; i < 4; i++) {
    v[i] = (bf2f((unsigned short)o0[i]) + bf2f((unsigned short)o1[i])) * w;
    mx = fmaxf(mx, fabsf(v[i]));
  }
  mx = wmaxr(mx);
  __shared__ float sh[4];
  if ((threadIdx.x & 63) == 0) sh[threadIdx.x >> 6] = mx;
  __syncthreads();
  float rmax = fmaxf(fmaxf(sh[0], sh[1]), fmaxf(sh[2], sh[3]));
  float s = 127.f / fmaxf(rmax, 1e-5f);
  float is = 1.f / s;
  unsigned pk = 0;
  for (int i = 0; i < 4; i++) {
    int ai = (int)fminf(fmaxf(rintf(v[i] * s), -128.f), 127.f);
    pk |= ((unsigned)ai & 0xFFu) << (8 * i);
  }
  *(unsigned*)&Oq[(size_t)row * 1024 + t4] = pk;
  if (threadIdx.x == 0) oscale[row] = is;
}

// ---------- i8 GEMM: double-buffered LDS, ONE barrier per K-iter ----------
// mode 0 (qkv): cols<2048 -> QK buffer (stride 2048); cols>=2048 -> V direct to VT
//               with the vtrans token permutation (swap bits 2<->3 of t) baked in.
// mode 1: outF = acc*dq + skip.
__global__ __launch_bounds__(256, 3) void gemm_i8(const signed char* __restrict__ A8,
                                                  const signed char* __restrict__ B8,
                                                  int N, int K, int nwg, int mode,
                                                  const float* __restrict__ rowsc,
                                                  const float* __restrict__ wscp,
                                                  const float* __restrict__ skip,
                                                  float* __restrict__ outF,
                                                  unsigned short* __restrict__ outB,
                                                  unsigned short* __restrict__ vtout) {
  __shared__ signed char As[2][128 * 64];
  __shared__ signed char Bs[2][128 * 64];
  int bid = blockIdx.x;
  int wg = (bid % 8) * (nwg >> 3) + (bid >> 3);   // XCD-chunked remap
  int bx = wg & 31, by = wg >> 5;                 // M=4096 -> 32 M-tiles
  int tid = threadIdx.x;
  int w = tid >> 6, l = tid & 63;
  int q = l & 15, g = l >> 4;
  int tm = bx * 128, tn = by * 128;
  int wr = w >> 1, wc = w & 1;
  float wsc = wscp[0];
  i32x4 acc[4][4];
  i32x4 zero = {0, 0, 0, 0};
#pragma unroll
  for (int m = 0; m < 4; m++)
#pragma unroll
    for (int n = 0; n < 4; n++) acc[m][n] = zero;
  int s0 = w * 64 + l, s1 = 256 + s0;
  int r0 = s0 >> 2, p0 = s0 & 3, gs0 = p0 ^ ((r0 >> 1) & 3);
  int r1 = s1 >> 2, p1 = s1 & 3, gs1 = p1 ^ ((r1 >> 1) & 3);
  const signed char* Ag0 = A8 + (size_t)(tm + r0) * K + gs0 * 16;
  const signed char* Ag1 = A8 + (size_t)(tm + r1) * K + gs1 * 16;
  const signed char* Bg0 = B8 + (size_t)(tn + r0) * K + gs0 * 16;
  const signed char* Bg1 = B8 + (size_t)(tn + r1) * K + gs1 * 16;
  int posq = ((q >> 1) & 3);

  auto stage = [&](int buf, int k0) {
    gload_lds16(Ag0 + k0, &As[buf][w * 1024]);
    gload_lds16(Ag1 + k0, &As[buf][4096 + w * 1024]);
    gload_lds16(Bg0 + k0, &Bs[buf][w * 1024]);
    gload_lds16(Bg1 + k0, &Bs[buf][4096 + w * 1024]);
  };

  stage(0, 0);
  __syncthreads();
  int cur = 0;
  for (int k0 = 0; k0 < K; k0 += 64) {
    if (k0 + 64 < K) stage(cur ^ 1, k0 + 64);     // prefetch overlaps MFMA
    int pg = (g ^ posq) * 16;
    i32x4 af[4], bfr[4];
#pragma unroll
    for (int m = 0; m < 4; m++)
      af[m] = *(const i32x4*)&As[cur][(wr * 64 + m * 16 + q) * 64 + pg];
#pragma unroll
    for (int n = 0; n < 4; n++)
      bfr[n] = *(const i32x4*)&Bs[cur][(wc * 64 + n * 16 + q) * 64 + pg];
#pragma unroll
    for (int m = 0; m < 4; m++)
#pragma unroll
      for (int n = 0; n < 4; n++)
        acc[m][n] = __builtin_amdgcn_mfma_i32_16x16x64_i8(af[m], bfr[n], acc[m][n], 0, 0, 0);
    __syncthreads();      // all waves done reading cur; prefetch vmcnt drained
    cur ^= 1;
  }
  if (mode == 0) {
#pragma unroll
    for (int m = 0; m < 4; m++) {
      int row0 = tm + wr * 64 + m * 16 + g * 4;
#pragma unroll
      for (int n = 0; n < 4; n++) {
        int col = tn + wc * 64 + n * 16 + q;
        if (col < 2048) {
#pragma unroll
          for (int r = 0; r < 4; r++) {
            int row = row0 + r;
            float vv = (float)acc[m][n][r] * (rowsc[row] * wsc);
            outB[(size_t)row * 2048 + col] = f2bf(vv);
          }
        } else {
          int h = (col - 2048) >> 6, e = col & 63;
          int t0 = row0 & 2047, b = row0 >> 11;
          int tp0 = (t0 & ~12) | ((t0 & 4) << 1) | ((t0 & 8) >> 1);  // swap bits 2<->3
          bf16x4 u;
#pragma unroll
          for (int r = 0; r < 4; r++) {
            int row = row0 + r;
            float vv = (float)acc[m][n][r] * (rowsc[row] * wsc);
            u[r] = (short)f2bf(vv);
          }
          *(bf16x4*)&vtout[((size_t)((b * 16 + h) * 64 + e)) * 2048 + tp0] = u;
        }
      }
    }
  } else {
#pragma unroll
    for (int m = 0; m < 4; m++) {
#pragma unroll
      for (int r = 0; r < 4; r++) {
        int row = tm + wr * 64 + m * 16 + g * 4 + r;
        float dq = rowsc[row] * wsc;
#pragma unroll
        for (int n = 0; n < 4; n++) {
          int col = tn + wc * 64 + n * 16 + q;
          size_t idx = (size_t)row * N + col;
          outF[idx] = (float)acc[m][n][r] * dq + skip[idx];
        }
      }
    }
  }
}

// ---------- prep v3: 4096 blocks, qk-norm+RoPE only (QK buffer stride 2048) ----------
// Block = one token: threads 0-127 Q-row, 128-255 K-row; thread = 8 contiguous elems
// of one head (head = 8-lane group). Norm: shfl_xor(1,2,4); partner = lane +-3.
__global__ __launch_bounds__(256) void prep_k(const unsigned short* __restrict__ qk,
                                              const float* __restrict__ pos,
                                              const float* __restrict__ scale,
                                              const float* __restrict__ freqs,
                                              unsigned short* __restrict__ Qo,
                                              unsigned short* __restrict__ Ko) {
  int tid = threadIdx.x;
  int t = blockIdx.x & 2047, b = blockIdx.x >> 11;
  int half = tid >> 7;            // 0 = Q, 1 = K
  int i = tid & 127;
  int h = i >> 3, j = i & 7;      // head, 8-elem slot (e = j*8..j*8+7)
  int lane = tid & 63;
  const unsigned short* src =
      qk + ((size_t)(b * 2048 + t)) * 2048 + half * 1024 + h * 64 + j * 8;
  bf16x8 vv = *(const bf16x8*)src;
  float f[8]; float ss = 0.f;
#pragma unroll
  for (int m = 0; m < 8; m++) { f[m] = bf2f((unsigned short)vv[m]); ss += f[m] * f[m]; }
  ss += __shfl_xor(ss, 1);
  ss += __shfl_xor(ss, 2);
  ss += __shfl_xor(ss, 4);        // full-head sum (8 lanes x 8 elems)
  float fac = sqrtf(scale[h]) * rsqrtf(ss + 1e-6f);
#pragma unroll
  for (int m = 0; m < 8; m++) f[m] *= fac;
  // partner exchange: e<24 -> e+24 (lane+3), 24<=e<48 -> e-24 (lane-3)
  int plane = (j < 3) ? lane + 3 : ((j < 6) ? lane - 3 : lane);
  float p[8];
#pragma unroll
  for (int m = 0; m < 8; m++) p[m] = __shfl(f[m], plane);
  float outv[8];
  if (j < 6) {
    int a = (j < 3) ? j : j - 3;
    float sgn = (j < 3) ? -1.f : 1.f;
    float pth = pos[((size_t)(b * 2048 + t)) * 3 + a];
    f32x4 fr0 = *(const f32x4*)&freqs[h * 8];
    f32x4 fr1 = *(const f32x4*)&freqs[h * 8 + 4];
#pragma unroll
    for (int m = 0; m < 8; m++) {
      float frq = (m < 4) ? fr0[m] : fr1[m - 4];
      float rev = fract_raw(pth * frq * INV2PI);   // sin(2*pi*rev) == sin(th)
      float sn = sin_rev(rev), cs = cos_rev(rev);
      outv[m] = f[m] * cs + sgn * p[m] * sn;
    }
  } else {
#pragma unroll
    for (int m = 0; m < 8; m++) outv[m] = f[m];
  }
  bf16x8 o;
  size_t oi = ((size_t)((b * 16 + h) * 2048 + t)) * 64 + j * 8;
  if (half == 0) {
#pragma unroll
    for (int m = 0; m < 8; m++) o[m] = (short)f2bf(outv[m] * LOG2E);  // exp2-softmax prescale
    *(bf16x8*)(Qo + oi) = o;
  } else {
#pragma unroll
    for (int m = 0; m < 8; m++) o[m] = (short)f2bf(outv[m]);
    *(bf16x8*)(Ko + oi) = o;
  }
}

// ---------- flash attention (frozen R17 form): KVBLK=128, XCD-local KV ----------
// grid 512; bid swizzle: all 8 qg-blocks of one (split,bh) share bid%8 -> same XCD L2.
// block 512 = 8 waves; wave = 32 Q-rows; P = 2^(S-15) exactly (|S_log2| <= 14.5).
__global__ __launch_bounds__(512, 4) void attn_k(const unsigned short* __restrict__ Q,
                                                 const unsigned short* __restrict__ K,
                                                 const unsigned short* __restrict__ VT,
                                                 unsigned short* __restrict__ Opart,
                                                 float* __restrict__ ms) {
  __shared__ unsigned short Ks[2][128 * 64];   // [ktok][e],  granule ^= (row&7)
  __shared__ unsigned short Vs[2][64 * 128];   // [e][ktok'], granule low3 ^= (row&7)
  const float M0 = 15.0f;
  int tid = threadIdx.x;
  int w = tid >> 6, l = tid & 63;
  int q = l & 31, hi = l >> 5;
  int bid = blockIdx.x;
  int sbh = (bid >> 6) * 8 + (bid & 7);
  int qg = (bid >> 3) & 7;
  int split = sbh >> 5, bh = sbh & 31;
  int qrow0 = qg * 256 + w * 32;
  const unsigned short* Kbase = K + (size_t)bh * 2048 * 64 + (size_t)split * 1024 * 64;
  const unsigned short* Vbase = VT + (size_t)bh * 64 * 2048 + split * 1024;

  bf16x8 qa[4];
#pragma unroll
  for (int s = 0; s < 4; s++)
    qa[s] = *(const bf16x8*)(Q + ((size_t)bh * 2048 + qrow0 + q) * 64 + s * 16 + hi * 8);

  int koff0[4], koff1[4], voff0[4], voff1[4];
#pragma unroll
  for (int se = 0; se < 4; se++) {
    int gk = se * 2 + hi;
    koff0[se] = q * 64 + ((gk ^ (q & 7)) * 8);
    koff1[se] = (32 + q) * 64 + ((gk ^ (q & 7)) * 8);
    voff0[se] = q * 128 + ((gk ^ (q & 7)) * 8);
    voff1[se] = (32 + q) * 128 + ((gk ^ (q & 7)) * 8);
  }

  int slA = tid, slB = 512 + tid;
  int krA = slA >> 3, kgA = (slA & 7) ^ (krA & 7);
  int krB = slB >> 3, kgB = (slB & 7) ^ (krB & 7);
  int vrA = slA >> 4, vgA = (slA & 15) ^ (vrA & 7);
  int vrB = slB >> 4, vgB = (slB & 15) ^ (vrB & 7);
  const unsigned short* KgA = Kbase + (size_t)krA * 64 + kgA * 8;
  const unsigned short* KgB = Kbase + (size_t)krB * 64 + kgB * 8;
  const unsigned short* VgA = Vbase + (size_t)vrA * 2048 + vgA * 8;
  const unsigned short* VgB = Vbase + (size_t)vrB * 2048 + vgB * 8;

  f32x16 acc0, acc1, fz;
  for (int i = 0; i < 16; i++) { acc0[i] = 0.f; acc1[i] = 0.f; fz[i] = 0.f; }
  float sum = 0.f;

  auto stage = [&](int buf, int kt) {
    gload_lds16(KgA + (size_t)kt * 64, &Ks[buf][(w * 64) * 8]);
    gload_lds16(KgB + (size_t)kt * 64, &Ks[buf][(512 + w * 64) * 8]);
    gload_lds16(VgA + kt, &Vs[buf][(w * 64) * 8]);
    gload_lds16(VgB + kt, &Vs[buf][(512 + w * 64) * 8]);
  };

  stage(0, 0);
  __syncthreads();
  int cur = 0;
  for (int it = 0; it < 8; it++) {
    if (it < 7) stage(cur ^ 1, (it + 1) * 128);
    const unsigned short* Ksc = Ks[cur];
    const unsigned short* Vsc = Vs[cur];
#pragma unroll
    for (int ss = 0; ss < 2; ss++) {
      int kro = ss * 4096;
      int vco = ss * 64;
      bf16x8 ka0 = *(const bf16x8*)&Ksc[kro + koff0[0]];
      bf16x8 ka1 = *(const bf16x8*)&Ksc[kro + koff1[0]];
      __builtin_amdgcn_s_setprio(1);
      f32x16 s0 = __builtin_amdgcn_mfma_f32_32x32x16_bf16(ka0, qa[0], fz, 0, 0, 0);
      f32x16 s1 = __builtin_amdgcn_mfma_f32_32x32x16_bf16(ka1, qa[0], fz, 0, 0, 0);
#pragma unroll
      for (int se = 1; se < 4; se++) {
        ka0 = *(const bf16x8*)&Ksc[kro + koff0[se]];
        ka1 = *(const bf16x8*)&Ksc[kro + koff1[se]];
        s0 = __builtin_amdgcn_mfma_f32_32x32x16_bf16(ka0, qa[se], s0, 0, 0, 0);
        s1 = __builtin_amdgcn_mfma_f32_32x32x16_bf16(ka1, qa[se], s1, 0, 0, 0);
      }
      __builtin_amdgcn_s_setprio(0);

      bf16x8 pf[4];
#pragma unroll
      for (int n = 0; n < 4; n++) {
        int o = (n & 1) * 8;
        u32x4 t;
#pragma unroll
        for (int j = 0; j < 4; j++) {
          float a = (n < 2) ? s0[o + 2 * j] : s1[o + 2 * j];
          float b = (n < 2) ? s0[o + 2 * j + 1] : s1[o + 2 * j + 1];
          float e0 = exp2raw(a - M0);
          float e1 = exp2raw(b - M0);
          sum += e0 + e1;
          t[j] = cvtpk(e0, e1);
        }
        pf[n] = __builtin_bit_cast(bf16x8, t);
      }

      __builtin_amdgcn_s_setprio(1);
#pragma unroll
      for (int n = 0; n < 4; n++) {
        bf16x8 va0 = *(const bf16x8*)&Vsc[vco + voff0[n]];
        bf16x8 va1 = *(const bf16x8*)&Vsc[vco + voff1[n]];
        acc0 = __builtin_amdgcn_mfma_f32_32x32x16_bf16(va0, pf[n], acc0, 0, 0, 0);
        acc1 = __builtin_amdgcn_mfma_f32_32x32x16_bf16(va1, pf[n], acc1, 0, 0, 0);
      }
      __builtin_amdgcn_s_setprio(0);
    }
    __syncthreads();
    cur ^= 1;
  }

  sum += __shfl_xor(sum, 32);
  size_t prow = (size_t)(split * 32 + bh) * 2048 + qrow0 + q;
  unsigned short* Op = Opart + prow * 64;
#pragma unroll
  for (int et = 0; et < 2; et++) {
    const f32x16& a = et ? acc1 : acc0;
#pragma unroll
    for (int qd = 0; qd < 4; qd++) {
      int e0 = et * 32 + 4 * hi + qd * 8;
      u32x2 t;
      t[0] = cvtpk(a[qd * 4 + 0], a[qd * 4 + 1]);
      t[1] = cvtpk(a[qd * 4 + 2], a[qd * 4 + 3]);
      *(bf16x4*)&Op[e0] = __builtin_bit_cast(bf16x4, t);
    }
  }
  if (hi == 0) ms[prow] = sum;
}

extern "C" void kernel_launch(void* const* d_in, const int* in_sizes, int n_in,
                              void* d_out, int out_size, void* d_ws, size_t ws_size,
                              hipStream_t stream) {
  const float* x      = (const float*)d_in[0];
  const float* pos    = (const float*)d_in[1];
  const float* cond   = (const float*)d_in[2];
  const float* norm_w = (const float*)d_in[3];
  const float* qkv_w  = (const float*)d_in[4];
  const float* out_w  = (const float*)d_in[5];
  const float* scale  = (const float*)d_in[6];
  const float* freqs  = (const float*)d_in[7];
  float* out = (float*)d_out;
  char* ws = (char*)d_ws;

  const size_t o_ada    = 0;
  const size_t o_rowsum = 8192;
  const size_t o_scales = 24576;
  const size_t o_ascale = 24832;
  const size_t o_oscale = 41216;
  const size_t o_Wq8    = 57600;
  const size_t o_Wo8    = o_Wq8 + 3145728;
  const size_t o_AqQ    = o_Wo8 + 1048576;
  const size_t o_qkv    = o_AqQ + 8388608;
  const size_t o_K      = o_qkv + 25165824;
  const size_t o_VT     = o_K + 8388608;

  float* ada            = (float*)(ws + o_ada);
  float* rowsum         = (float*)(ws + o_rowsum);
  float* scales         = (float*)(ws + o_scales);
  float* ascale         = (float*)(ws + o_ascale);
  float* oscale         = (float*)(ws + o_oscale);
  signed char* Wq8      = (signed char*)(ws + o_Wq8);
  signed char* Wo8      = (signed char*)(ws + o_Wo8);
  signed char* Aq8      = (signed char*)(ws + o_AqQ);
  unsigned short* Qb    = (unsigned short*)(ws + o_AqQ);
  unsigned short* qk    = (unsigned short*)(ws + o_qkv);   // QK only, stride 2048 (16.78 MB)
  unsigned short* Opart = (unsigned short*)(ws + o_qkv);   // reuse after prep
  float* msb            = (float*)(ws + o_qkv + 2ull*32*2048*64*2);
  unsigned short* Kb    = (unsigned short*)(ws + o_K);
  signed char* Oq8      = (signed char*)(ws + o_K);        // reuse after attention
  unsigned short* VT    = (unsigned short*)(ws + o_VT);

  wrada_k<<<4608, 256, 0, stream>>>(qkv_w, out_w, cond, norm_w, rowsum, ada);
  finalize_k<<<1, 256, 0, stream>>>(rowsum, scales);
  wqrms_k<<<8192, 256, 0, stream>>>(qkv_w, out_w, scales, x, ada, Wq8, Wo8, Aq8, ascale);
  gemm_i8<<<768, 256, 0, stream>>>(Aq8, Wq8, 3072, 1024, 768, 0, ascale, &scales[0],
                                   nullptr, nullptr, qk, VT);
  prep_k<<<4096, 256, 0, stream>>>(qk, pos, scale, freqs, Qb, Kb);
  attn_k<<<512, 512, 0, stream>>>(Qb, Kb, VT, Opart, msb);
  oquant_k<<<4096, 256, 0, stream>>>(Opart, msb, Oq8, oscale);
  gemm_i8<<<256, 256, 0, stream>>>(Oq8, Wo8, 1024, 1024, 256, 1, oscale, &scales[2],
                                   x, out, nullptr, nullptr);
}

// Round 21
// 126.028 us; speedup vs baseline: 1.3171x; 1.0661x over previous
//
#include <hip/hip_runtime.h>
#include <hip/hip_bf16.h>
#include <math.h>

typedef __attribute__((ext_vector_type(8))) short bf16x8;
typedef __attribute__((ext_vector_type(4))) short bf16x4;
typedef __attribute__((ext_vector_type(4))) float f32x4;
typedef __attribute__((ext_vector_type(16))) float f32x16;
typedef __attribute__((ext_vector_type(4))) unsigned u32x4;
typedef __attribute__((ext_vector_type(2))) unsigned u32x2;
typedef __attribute__((ext_vector_type(4))) int i32x4;

#define DEV static __device__ __forceinline__
#define LOG2E 1.4426950408889634f
#define INV2PI 0.15915494309189535f

DEV unsigned short f2bf(float f) {
  unsigned int u = __float_as_uint(f);
  u += 0x7FFFu + ((u >> 16) & 1u);   // RNE, inputs finite
  return (unsigned short)(u >> 16);
}
DEV float bf2f(unsigned short h) { return __uint_as_float(((unsigned int)h) << 16); }
DEV unsigned cvtpk(float lo, float hi) {
  unsigned r;
  asm("v_cvt_pk_bf16_f32 %0, %1, %2" : "=v"(r) : "v"(lo), "v"(hi));
  return r;
}
DEV float exp2raw(float x) {            // inputs in [-30,0]: no fixup needed
  float r;
  asm("v_exp_f32 %0, %1" : "=v"(r) : "v"(x));
  return r;
}
DEV float fract_raw(float x) { float r; asm("v_fract_f32 %0, %1" : "=v"(r) : "v"(x)); return r; }
DEV float sin_rev(float x)   { float r; asm("v_sin_f32 %0, %1"   : "=v"(r) : "v"(x)); return r; }
DEV float cos_rev(float x)   { float r; asm("v_cos_f32 %0, %1"   : "=v"(r) : "v"(x)); return r; }
DEV float wsum(float v) { for (int o = 32; o; o >>= 1) v += __shfl_xor(v, o); return v; }
DEV float wmaxr(float v) { for (int o = 32; o; o >>= 1) v = fmaxf(v, __shfl_xor(v, o)); return v; }

// async global->LDS, 16B per lane; dest = wave-uniform base + lane*16
DEV void gload_lds16(const void* g, void* s) {
  __builtin_amdgcn_global_load_lds(
      (const __attribute__((address_space(1))) unsigned int*)g,
      (__attribute__((address_space(3))) unsigned int*)s, 16, 0, 0);
}

// ---------- k1: blocks [0,4096) per-row |w| sums; [4096,4608) ada ----------
__global__ __launch_bounds__(256) void wrada_k(const float* __restrict__ qw,
                                               const float* __restrict__ ow,
                                               const float* __restrict__ cond,
                                               const float* __restrict__ nw,
                                               float* __restrict__ rowsum,
                                               float* __restrict__ ada) {
  if (blockIdx.x < 4096) {
    int row = blockIdx.x;  // 0..3071 -> qkv_w, 3072..4095 -> out_w
    const float* p = (row < 3072) ? (qw + (size_t)row * 1024)
                                  : (ow + (size_t)(row - 3072) * 1024);
    f32x4 v = *(const f32x4*)&p[threadIdx.x * 4];
    float s = fabsf(v[0]) + fabsf(v[1]) + fabsf(v[2]) + fabsf(v[3]);
    s = wsum(s);
    __shared__ float sh[4];
    if ((threadIdx.x & 63) == 0) sh[threadIdx.x >> 6] = s;
    __syncthreads();
    if (threadIdx.x == 0) rowsum[row] = sh[0] + sh[1] + sh[2] + sh[3];
  } else {
    int bid2 = blockIdx.x - 4096;          // 0..511
    int b = bid2 >> 8;
    int j = (bid2 & 255) * 4 + (threadIdx.x >> 6);
    int l = threadIdx.x & 63;
    const float* cp = cond + b * 1024;
    const float* wp = nw + (size_t)j * 1024;
    float s = 0.f;
    for (int c = l; c < 1024; c += 64) s += cp[c] * wp[c];
    s = wsum(s);
    if (l == 0) ada[b * 1024 + j] = 1.f + s;
  }
}

__global__ __launch_bounds__(256) void finalize_k(const float* __restrict__ rowsum,
                                                  float* __restrict__ scales) {
  float s1 = 0.f, s2 = 0.f;
  for (int i = threadIdx.x; i < 3072; i += 256) s1 += rowsum[i];
  for (int i = threadIdx.x; i < 1024; i += 256) s2 += rowsum[3072 + i];
  s1 = wsum(s1); s2 = wsum(s2);
  __shared__ float sh1[4], sh2[4];
  if ((threadIdx.x & 63) == 0) { sh1[threadIdx.x >> 6] = s1; sh2[threadIdx.x >> 6] = s2; }
  __syncthreads();
  if (threadIdx.x == 0) {
    float m1 = fmaxf((sh1[0] + sh1[1] + sh1[2] + sh1[3]) / (3072.f * 1024.f), 1e-5f);
    float m2 = fmaxf((sh2[0] + sh2[1] + sh2[2] + sh2[3]) / (1024.f * 1024.f), 1e-5f);
    scales[0] = m1; scales[1] = 1.f / m1;   // qkv_w: mean, 1/mean
    scales[2] = m2; scales[3] = 1.f / m2;   // out_w
  }
}

// ---------- k2: blocks [0,4096) ternary wquant -> i8; [4096,8192) RMSNorm+act_quant ----------
__global__ __launch_bounds__(256) void wqrms_k(const float* __restrict__ qw,
                                               const float* __restrict__ ow,
                                               const float* __restrict__ scales,
                                               const float* __restrict__ x,
                                               const float* __restrict__ ada,
                                               signed char* __restrict__ Wq,
                                               signed char* __restrict__ Wo,
                                               signed char* __restrict__ Aq,
                                               float* __restrict__ ascale) {
  if (blockIdx.x < 4096) {
    int i0 = (blockIdx.x * 256 + threadIdx.x) * 4;
    if (i0 < 3072 * 1024) {
      f32x4 v = *(const f32x4*)&qw[i0];
      unsigned pk = 0;
      for (int j = 0; j < 4; j++) {
        int t = (int)fminf(fmaxf(rintf(v[j] * scales[1]), -1.f), 1.f);
        pk |= ((unsigned)t & 0xFFu) << (8 * j);
      }
      *(unsigned*)&Wq[i0] = pk;
    } else {
      int k = i0 - 3072 * 1024;
      f32x4 v = *(const f32x4*)&ow[k];
      unsigned pk = 0;
      for (int j = 0; j < 4; j++) {
        int t = (int)fminf(fmaxf(rintf(v[j] * scales[3]), -1.f), 1.f);
        pk |= ((unsigned)t & 0xFFu) << (8 * j);
      }
      *(unsigned*)&Wo[k] = pk;
    }
  } else {
    int row = blockIdx.x - 4096;   // b*2048 + t
    int b = row >> 11;
    const float* xr = x + (size_t)row * 1024;
    const float* ar = ada + b * 1024;
    int t4 = threadIdx.x * 4;
    f32x4 v = *(const f32x4*)&xr[t4];
    float ss = v[0]*v[0] + v[1]*v[1] + v[2]*v[2] + v[3]*v[3];
    ss = wsum(ss);
    __shared__ float sh[4], sh2[4];
    if ((threadIdx.x & 63) == 0) sh[threadIdx.x >> 6] = ss;
    __syncthreads();
    float inv = rsqrtf((sh[0] + sh[1] + sh[2] + sh[3]) * (1.f / 1024.f) + 1e-6f);
    f32x4 a = *(const f32x4*)&ar[t4];
    float xn[4]; float mx = 0.f;
    for (int i = 0; i < 4; i++) { xn[i] = v[i] * a[i] * inv; mx = fmaxf(mx, fabsf(xn[i])); }
    mx = wmaxr(mx);
    if ((threadIdx.x & 63) == 0) sh2[threadIdx.x >> 6] = mx;
    __syncthreads();
    float rmax = fmaxf(fmaxf(sh2[0], sh2[1]), fmaxf(sh2[2], sh2[3]));
    float s = 127.f / fmaxf(rmax, 1e-5f);
    unsigned pk = 0;
    for (int i = 0; i < 4; i++) {
      int ai = (int)fminf(fmaxf(rintf(xn[i] * s), -128.f), 127.f);
      pk |= ((unsigned)ai & 0xFFu) << (8 * i);
    }
    *(unsigned*)&Aq[(size_t)row * 1024 + t4] = pk;
    if (threadIdx.x == 0) ascale[row] = 1.f / s;
  }
}

// ---------- combine split-K partials + act_quant -> int8 ----------
__global__ __launch_bounds__(256) void oquant_k(const unsigned short* __restrict__ Opart,
                                                const float* __restrict__ ms,
                                                signed char* __restrict__ Oq,
                                                float* __restrict__ oscale) {
  int row = blockIdx.x;            // b*2048 + t
  int b = row >> 11, qrow = row & 2047;
  int t4 = threadIdx.x * 4;
  int h = t4 >> 6, e0 = t4 & 63;
  int bh = b * 16 + h;
  size_t i0 = (size_t)bh * 2048 + qrow;             // split 0
  size_t i1 = (size_t)(32 + bh) * 2048 + qrow;      // split 1
  float w = 1.f / (ms[i0] + ms[i1]);                // common 2^-15 factor cancels
  bf16x4 o0 = *(const bf16x4*)&Opart[i0 * 64 + e0];
  bf16x4 o1 = *(const bf16x4*)&Opart[i1 * 64 + e0];
  float v[4]; float mx = 0.f;
  for (int i = 0; i < 4; i++) {
    v[i] = (bf2f((unsigned short)o0[i]) + bf2f((unsigned short)o1[i])) * w;
    mx = fmaxf(mx, fabsf(v[i]));
  }
  mx = wmaxr(mx);
  __shared__ float sh[4];
  if ((threadIdx.x & 63) == 0) sh[threadIdx.x >> 6] = mx;
  __syncthreads();
  float rmax = fmaxf(fmaxf(sh[0], sh[1]), fmaxf(sh[2], sh[3]));
  float s = 127.f / fmaxf(rmax, 1e-5f);
  float is = 1.f / s;
  unsigned pk = 0;
  for (int i = 0; i < 4; i++) {
    int ai = (int)fminf(fmaxf(rintf(v[i] * s), -128.f), 127.f);
    pk |= ((unsigned)ai & 0xFFu) << (8 * i);
  }
  *(unsigned*)&Oq[(size_t)row * 1024 + t4] = pk;
  if (threadIdx.x == 0) oscale[row] = is;
}

// ---------- i8 GEMM (128x128): double-buffered LDS, ONE barrier per K-iter ----------
// mode 0 (qkv): cols<2048 -> QK buffer (stride 2048); cols>=2048 -> V direct to VT
//               with the vtrans token permutation (swap bits 2<->3 of t) baked in.
__global__ __launch_bounds__(256, 3) void gemm_i8(const signed char* __restrict__ A8,
                                                  const signed char* __restrict__ B8,
                                                  int N, int K, int nwg, int mode,
                                                  const float* __restrict__ rowsc,
                                                  const float* __restrict__ wscp,
                                                  const float* __restrict__ skip,
                                                  float* __restrict__ outF,
                                                  unsigned short* __restrict__ outB,
                                                  unsigned short* __restrict__ vtout) {
  __shared__ signed char As[2][128 * 64];
  __shared__ signed char Bs[2][128 * 64];
  int bid = blockIdx.x;
  int wg = (bid % 8) * (nwg >> 3) + (bid >> 3);   // XCD-chunked remap
  int bx = wg & 31, by = wg >> 5;                 // M=4096 -> 32 M-tiles
  int tid = threadIdx.x;
  int w = tid >> 6, l = tid & 63;
  int q = l & 15, g = l >> 4;
  int tm = bx * 128, tn = by * 128;
  int wr = w >> 1, wc = w & 1;
  float wsc = wscp[0];
  i32x4 acc[4][4];
  i32x4 zero = {0, 0, 0, 0};
#pragma unroll
  for (int m = 0; m < 4; m++)
#pragma unroll
    for (int n = 0; n < 4; n++) acc[m][n] = zero;
  int s0 = w * 64 + l, s1 = 256 + s0;
  int r0 = s0 >> 2, p0 = s0 & 3, gs0 = p0 ^ ((r0 >> 1) & 3);
  int r1 = s1 >> 2, p1 = s1 & 3, gs1 = p1 ^ ((r1 >> 1) & 3);
  const signed char* Ag0 = A8 + (size_t)(tm + r0) * K + gs0 * 16;
  const signed char* Ag1 = A8 + (size_t)(tm + r1) * K + gs1 * 16;
  const signed char* Bg0 = B8 + (size_t)(tn + r0) * K + gs0 * 16;
  const signed char* Bg1 = B8 + (size_t)(tn + r1) * K + gs1 * 16;
  int posq = ((q >> 1) & 3);

  auto stage = [&](int buf, int k0) {
    gload_lds16(Ag0 + k0, &As[buf][w * 1024]);
    gload_lds16(Ag1 + k0, &As[buf][4096 + w * 1024]);
    gload_lds16(Bg0 + k0, &Bs[buf][w * 1024]);
    gload_lds16(Bg1 + k0, &Bs[buf][4096 + w * 1024]);
  };

  stage(0, 0);
  __syncthreads();
  int cur = 0;
  for (int k0 = 0; k0 < K; k0 += 64) {
    if (k0 + 64 < K) stage(cur ^ 1, k0 + 64);     // prefetch overlaps MFMA
    int pg = (g ^ posq) * 16;
    i32x4 af[4], bfr[4];
#pragma unroll
    for (int m = 0; m < 4; m++)
      af[m] = *(const i32x4*)&As[cur][(wr * 64 + m * 16 + q) * 64 + pg];
#pragma unroll
    for (int n = 0; n < 4; n++)
      bfr[n] = *(const i32x4*)&Bs[cur][(wc * 64 + n * 16 + q) * 64 + pg];
#pragma unroll
    for (int m = 0; m < 4; m++)
#pragma unroll
      for (int n = 0; n < 4; n++)
        acc[m][n] = __builtin_amdgcn_mfma_i32_16x16x64_i8(af[m], bfr[n], acc[m][n], 0, 0, 0);
    __syncthreads();      // all waves done reading cur; prefetch vmcnt drained
    cur ^= 1;
  }
  if (mode == 0) {
#pragma unroll
    for (int m = 0; m < 4; m++) {
      int row0 = tm + wr * 64 + m * 16 + g * 4;
#pragma unroll
      for (int n = 0; n < 4; n++) {
        int col = tn + wc * 64 + n * 16 + q;
        if (col < 2048) {
#pragma unroll
          for (int r = 0; r < 4; r++) {
            int row = row0 + r;
            float vv = (float)acc[m][n][r] * (rowsc[row] * wsc);
            outB[(size_t)row * 2048 + col] = f2bf(vv);
          }
        } else {
          int h = (col - 2048) >> 6, e = col & 63;
          int t0 = row0 & 2047, b = row0 >> 11;
          int tp0 = (t0 & ~12) | ((t0 & 4) << 1) | ((t0 & 8) >> 1);  // swap bits 2<->3
          bf16x4 u;
#pragma unroll
          for (int r = 0; r < 4; r++) {
            int row = row0 + r;
            float vv = (float)acc[m][n][r] * (rowsc[row] * wsc);
            u[r] = (short)f2bf(vv);
          }
          *(bf16x4*)&vtout[((size_t)((b * 16 + h) * 64 + e)) * 2048 + tp0] = u;
        }
      }
    }
  } else {
#pragma unroll
    for (int m = 0; m < 4; m++) {
#pragma unroll
      for (int r = 0; r < 4; r++) {
        int row = tm + wr * 64 + m * 16 + g * 4 + r;
        float dq = rowsc[row] * wsc;
#pragma unroll
        for (int n = 0; n < 4; n++) {
          int col = tn + wc * 64 + n * 16 + q;
          size_t idx = (size_t)row * N + col;
          outF[idx] = (float)acc[m][n][r] * dq + skip[idx];
        }
      }
    }
  }
}

// ---------- i8 GEMM (128x64 tile): for N=1024 output proj -> 512 blocks, 2/CU ----------
// 4 waves each own a 64x32 quadrant (acc[4][2]); outF = acc*dq + skip.
__global__ __launch_bounds__(256, 3) void gemm_i8_n64(const signed char* __restrict__ A8,
                                                      const signed char* __restrict__ B8,
                                                      int N, int K, int nwg,
                                                      const float* __restrict__ rowsc,
                                                      const float* __restrict__ wscp,
                                                      const float* __restrict__ skip,
                                                      float* __restrict__ outF) {
  __shared__ signed char As[2][128 * 64];   // 8 KB per buf
  __shared__ signed char Bs[2][64 * 64];    // 4 KB per buf
  int bid = blockIdx.x;
  int wg = (bid % 8) * (nwg >> 3) + (bid >> 3);   // XCD-chunked remap (512 % 8 == 0)
  int bx = wg & 31, by = wg >> 5;                 // 32 M-tiles x 16 N-tiles
  int tid = threadIdx.x;
  int w = tid >> 6, l = tid & 63;
  int q = l & 15, g = l >> 4;
  int tm = bx * 128, tn = by * 64;
  int wr = w >> 1, wc = w & 1;                    // 64-row, 32-col quadrant
  float wsc = wscp[0];
  i32x4 acc[4][2];
  i32x4 zero = {0, 0, 0, 0};
#pragma unroll
  for (int m = 0; m < 4; m++)
#pragma unroll
    for (int n = 0; n < 2; n++) acc[m][n] = zero;
  // A staging: 512 slots (2/thread); B staging: 256 slots (1/thread)
  int s0 = w * 64 + l, s1 = 256 + s0;
  int r0 = s0 >> 2, p0 = s0 & 3, gs0 = p0 ^ ((r0 >> 1) & 3);
  int r1 = s1 >> 2, p1 = s1 & 3, gs1 = p1 ^ ((r1 >> 1) & 3);
  const signed char* Ag0 = A8 + (size_t)(tm + r0) * K + gs0 * 16;
  const signed char* Ag1 = A8 + (size_t)(tm + r1) * K + gs1 * 16;
  const signed char* Bg0 = B8 + (size_t)(tn + r0) * K + gs0 * 16;   // r0 < 64 for s0 < 256
  int posq = ((q >> 1) & 3);

  auto stage = [&](int buf, int k0) {
    gload_lds16(Ag0 + k0, &As[buf][w * 1024]);
    gload_lds16(Ag1 + k0, &As[buf][4096 + w * 1024]);
    gload_lds16(Bg0 + k0, &Bs[buf][w * 1024]);
  };

  stage(0, 0);
  __syncthreads();
  int cur = 0;
  for (int k0 = 0; k0 < K; k0 += 64) {
    if (k0 + 64 < K) stage(cur ^ 1, k0 + 64);     // prefetch overlaps MFMA
    int pg = (g ^ posq) * 16;
    i32x4 af[4], bfr[2];
#pragma unroll
    for (int m = 0; m < 4; m++)
      af[m] = *(const i32x4*)&As[cur][(wr * 64 + m * 16 + q) * 64 + pg];
#pragma unroll
    for (int n = 0; n < 2; n++)
      bfr[n] = *(const i32x4*)&Bs[cur][(wc * 32 + n * 16 + q) * 64 + pg];
#pragma unroll
    for (int m = 0; m < 4; m++)
#pragma unroll
      for (int n = 0; n < 2; n++)
        acc[m][n] = __builtin_amdgcn_mfma_i32_16x16x64_i8(af[m], bfr[n], acc[m][n], 0, 0, 0);
    __syncthreads();
    cur ^= 1;
  }
#pragma unroll
  for (int m = 0; m < 4; m++) {
#pragma unroll
    for (int r = 0; r < 4; r++) {
      int row = tm + wr * 64 + m * 16 + g * 4 + r;
      float dq = rowsc[row] * wsc;
#pragma unroll
      for (int n = 0; n < 2; n++) {
        int col = tn + wc * 32 + n * 16 + q;
        size_t idx = (size_t)row * N + col;
        outF[idx] = (float)acc[m][n][r] * dq + skip[idx];
      }
    }
  }
}

// ---------- prep v3: 4096 blocks, qk-norm+RoPE only (QK buffer stride 2048) ----------
__global__ __launch_bounds__(256) void prep_k(const unsigned short* __restrict__ qk,
                                              const float* __restrict__ pos,
                                              const float* __restrict__ scale,
                                              const float* __restrict__ freqs,
                                              unsigned short* __restrict__ Qo,
                                              unsigned short* __restrict__ Ko) {
  int tid = threadIdx.x;
  int t = blockIdx.x & 2047, b = blockIdx.x >> 11;
  int half = tid >> 7;            // 0 = Q, 1 = K
  int i = tid & 127;
  int h = i >> 3, j = i & 7;      // head, 8-elem slot (e = j*8..j*8+7)
  int lane = tid & 63;
  const unsigned short* src =
      qk + ((size_t)(b * 2048 + t)) * 2048 + half * 1024 + h * 64 + j * 8;
  bf16x8 vv = *(const bf16x8*)src;
  float f[8]; float ss = 0.f;
#pragma unroll
  for (int m = 0; m < 8; m++) { f[m] = bf2f((unsigned short)vv[m]); ss += f[m] * f[m]; }
  ss += __shfl_xor(ss, 1);
  ss += __shfl_xor(ss, 2);
  ss += __shfl_xor(ss, 4);        // full-head sum (8 lanes x 8 elems)
  float fac = sqrtf(scale[h]) * rsqrtf(ss + 1e-6f);
#pragma unroll
  for (int m = 0; m < 8; m++) f[m] *= fac;
  // partner exchange: e<24 -> e+24 (lane+3), 24<=e<48 -> e-24 (lane-3)
  int plane = (j < 3) ? lane + 3 : ((j < 6) ? lane - 3 : lane);
  float p[8];
#pragma unroll
  for (int m = 0; m < 8; m++) p[m] = __shfl(f[m], plane);
  float outv[8];
  if (j < 6) {
    int a = (j < 3) ? j : j - 3;
    float sgn = (j < 3) ? -1.f : 1.f;
    float pth = pos[((size_t)(b * 2048 + t)) * 3 + a];
    f32x4 fr0 = *(const f32x4*)&freqs[h * 8];
    f32x4 fr1 = *(const f32x4*)&freqs[h * 8 + 4];
#pragma unroll
    for (int m = 0; m < 8; m++) {
      float frq = (m < 4) ? fr0[m] : fr1[m - 4];
      float rev = fract_raw(pth * frq * INV2PI);   // sin(2*pi*rev) == sin(th)
      float sn = sin_rev(rev), cs = cos_rev(rev);
      outv[m] = f[m] * cs + sgn * p[m] * sn;
    }
  } else {
#pragma unroll
    for (int m = 0; m < 8; m++) outv[m] = f[m];
  }
  bf16x8 o;
  size_t oi = ((size_t)((b * 16 + h) * 2048 + t)) * 64 + j * 8;
  if (half == 0) {
#pragma unroll
    for (int m = 0; m < 8; m++) o[m] = (short)f2bf(outv[m] * LOG2E);  // exp2-softmax prescale
    *(bf16x8*)(Qo + oi) = o;
  } else {
#pragma unroll
    for (int m = 0; m < 8; m++) o[m] = (short)f2bf(outv[m]);
    *(bf16x8*)(Ko + oi) = o;
  }
}

// ---------- flash attention (frozen R17 form): KVBLK=128, XCD-local KV ----------
__global__ __launch_bounds__(512, 4) void attn_k(const unsigned short* __restrict__ Q,
                                                 const unsigned short* __restrict__ K,
                                                 const unsigned short* __restrict__ VT,
                                                 unsigned short* __restrict__ Opart,
                                                 float* __restrict__ ms) {
  __shared__ unsigned short Ks[2][128 * 64];   // [ktok][e],  granule ^= (row&7)
  __shared__ unsigned short Vs[2][64 * 128];   // [e][ktok'], granule low3 ^= (row&7)
  const float M0 = 15.0f;
  int tid = threadIdx.x;
  int w = tid >> 6, l = tid & 63;
  int q = l & 31, hi = l >> 5;
  int bid = blockIdx.x;
  int sbh = (bid >> 6) * 8 + (bid & 7);
  int qg = (bid >> 3) & 7;
  int split = sbh >> 5, bh = sbh & 31;
  int qrow0 = qg * 256 + w * 32;
  const unsigned short* Kbase = K + (size_t)bh * 2048 * 64 + (size_t)split * 1024 * 64;
  const unsigned short* Vbase = VT + (size_t)bh * 64 * 2048 + split * 1024;

  bf16x8 qa[4];
#pragma unroll
  for (int s = 0; s < 4; s++)
    qa[s] = *(const bf16x8*)(Q + ((size_t)bh * 2048 + qrow0 + q) * 64 + s * 16 + hi * 8);

  int koff0[4], koff1[4], voff0[4], voff1[4];
#pragma unroll
  for (int se = 0; se < 4; se++) {
    int gk = se * 2 + hi;
    koff0[se] = q * 64 + ((gk ^ (q & 7)) * 8);
    koff1[se] = (32 + q) * 64 + ((gk ^ (q & 7)) * 8);
    voff0[se] = q * 128 + ((gk ^ (q & 7)) * 8);
    voff1[se] = (32 + q) * 128 + ((gk ^ (q & 7)) * 8);
  }

  int slA = tid, slB = 512 + tid;
  int krA = slA >> 3, kgA = (slA & 7) ^ (krA & 7);
  int krB = slB >> 3, kgB = (slB & 7) ^ (krB & 7);
  int vrA = slA >> 4, vgA = (slA & 15) ^ (vrA & 7);
  int vrB = slB >> 4, vgB = (slB & 15) ^ (vrB & 7);
  const unsigned short* KgA = Kbase + (size_t)krA * 64 + kgA * 8;
  const unsigned short* KgB = Kbase + (size_t)krB * 64 + kgB * 8;
  const unsigned short* VgA = Vbase + (size_t)vrA * 2048 + vgA * 8;
  const unsigned short* VgB = Vbase + (size_t)vrB * 2048 + vgB * 8;

  f32x16 acc0, acc1, fz;
  for (int i = 0; i < 16; i++) { acc0[i] = 0.f; acc1[i] = 0.f; fz[i] = 0.f; }
  float sum = 0.f;

  auto stage = [&](int buf, int kt) {
    gload_lds16(KgA + (size_t)kt * 64, &Ks[buf][(w * 64) * 8]);
    gload_lds16(KgB + (size_t)kt * 64, &Ks[buf][(512 + w * 64) * 8]);
    gload_lds16(VgA + kt, &Vs[buf][(w * 64) * 8]);
    gload_lds16(VgB + kt, &Vs[buf][(512 + w * 64) * 8]);
  };

  stage(0, 0);
  __syncthreads();
  int cur = 0;
  for (int it = 0; it < 8; it++) {
    if (it < 7) stage(cur ^ 1, (it + 1) * 128);
    const unsigned short* Ksc = Ks[cur];
    const unsigned short* Vsc = Vs[cur];
#pragma unroll
    for (int ss = 0; ss < 2; ss++) {
      int kro = ss * 4096;
      int vco = ss * 64;
      bf16x8 ka0 = *(const bf16x8*)&Ksc[kro + koff0[0]];
      bf16x8 ka1 = *(const bf16x8*)&Ksc[kro + koff1[0]];
      __builtin_amdgcn_s_setprio(1);
      f32x16 s0 = __builtin_amdgcn_mfma_f32_32x32x16_bf16(ka0, qa[0], fz, 0, 0, 0);
      f32x16 s1 = __builtin_amdgcn_mfma_f32_32x32x16_bf16(ka1, qa[0], fz, 0, 0, 0);
#pragma unroll
      for (int se = 1; se < 4; se++) {
        ka0 = *(const bf16x8*)&Ksc[kro + koff0[se]];
        ka1 = *(const bf16x8*)&Ksc[kro + koff1[se]];
        s0 = __builtin_amdgcn_mfma_f32_32x32x16_bf16(ka0, qa[se], s0, 0, 0, 0);
        s1 = __builtin_amdgcn_mfma_f32_32x32x16_bf16(ka1, qa[se], s1, 0, 0, 0);
      }
      __builtin_amdgcn_s_setprio(0);

      bf16x8 pf[4];
#pragma unroll
      for (int n = 0; n < 4; n++) {
        int o = (n & 1) * 8;
        u32x4 t;
#pragma unroll
        for (int j = 0; j < 4; j++) {
          float a = (n < 2) ? s0[o + 2 * j] : s1[o + 2 * j];
          float b = (n < 2) ? s0[o + 2 * j + 1] : s1[o + 2 * j + 1];
          float e0 = exp2raw(a - M0);
          float e1 = exp2raw(b - M0);
          sum += e0 + e1;
          t[j] = cvtpk(e0, e1);
        }
        pf[n] = __builtin_bit_cast(bf16x8, t);
      }

      __builtin_amdgcn_s_setprio(1);
#pragma unroll
      for (int n = 0; n < 4; n++) {
        bf16x8 va0 = *(const bf16x8*)&Vsc[vco + voff0[n]];
        bf16x8 va1 = *(const bf16x8*)&Vsc[vco + voff1[n]];
        acc0 = __builtin_amdgcn_mfma_f32_32x32x16_bf16(va0, pf[n], acc0, 0, 0, 0);
        acc1 = __builtin_amdgcn_mfma_f32_32x32x16_bf16(va1, pf[n], acc1, 0, 0, 0);
      }
      __builtin_amdgcn_s_setprio(0);
    }
    __syncthreads();
    cur ^= 1;
  }

  sum += __shfl_xor(sum, 32);
  size_t prow = (size_t)(split * 32 + bh) * 2048 + qrow0 + q;
  unsigned short* Op = Opart + prow * 64;
#pragma unroll
  for (int et = 0; et < 2; et++) {
    const f32x16& a = et ? acc1 : acc0;
#pragma unroll
    for (int qd = 0; qd < 4; qd++) {
      int e0 = et * 32 + 4 * hi + qd * 8;
      u32x2 t;
      t[0] = cvtpk(a[qd * 4 + 0], a[qd * 4 + 1]);
      t[1] = cvtpk(a[qd * 4 + 2], a[qd * 4 + 3]);
      *(bf16x4*)&Op[e0] = __builtin_bit_cast(bf16x4, t);
    }
  }
  if (hi == 0) ms[prow] = sum;
}

extern "C" void kernel_launch(void* const* d_in, const int* in_sizes, int n_in,
                              void* d_out, int out_size, void* d_ws, size_t ws_size,
                              hipStream_t stream) {
  const float* x      = (const float*)d_in[0];
  const float* pos    = (const float*)d_in[1];
  const float* cond   = (const float*)d_in[2];
  const float* norm_w = (const float*)d_in[3];
  const float* qkv_w  = (const float*)d_in[4];
  const float* out_w  = (const float*)d_in[5];
  const float* scale  = (const float*)d_in[6];
  const float* freqs  = (const float*)d_in[7];
  float* out = (float*)d_out;
  char* ws = (char*)d_ws;

  const size_t o_ada    = 0;
  const size_t o_rowsum = 8192;
  const size_t o_scales = 24576;
  const size_t o_ascale = 24832;
  const size_t o_oscale = 41216;
  const size_t o_Wq8    = 57600;
  const size_t o_Wo8    = o_Wq8 + 3145728;
  const size_t o_AqQ    = o_Wo8 + 1048576;
  const size_t o_qkv    = o_AqQ + 8388608;
  const size_t o_K      = o_qkv + 25165824;
  const size_t o_VT     = o_K + 8388608;

  float* ada            = (float*)(ws + o_ada);
  float* rowsum         = (float*)(ws + o_rowsum);
  float* scales         = (float*)(ws + o_scales);
  float* ascale         = (float*)(ws + o_ascale);
  float* oscale         = (float*)(ws + o_oscale);
  signed char* Wq8      = (signed char*)(ws + o_Wq8);
  signed char* Wo8      = (signed char*)(ws + o_Wo8);
  signed char* Aq8      = (signed char*)(ws + o_AqQ);
  unsigned short* Qb    = (unsigned short*)(ws + o_AqQ);
  unsigned short* qk    = (unsigned short*)(ws + o_qkv);   // QK only, stride 2048 (16.78 MB)
  unsigned short* Opart = (unsigned short*)(ws + o_qkv);   // reuse after prep
  float* msb            = (float*)(ws + o_qkv + 2ull*32*2048*64*2);
  unsigned short* Kb    = (unsigned short*)(ws + o_K);
  signed char* Oq8      = (signed char*)(ws + o_K);        // reuse after attention
  unsigned short* VT    = (unsigned short*)(ws + o_VT);

  wrada_k<<<4608, 256, 0, stream>>>(qkv_w, out_w, cond, norm_w, rowsum, ada);
  finalize_k<<<1, 256, 0, stream>>>(rowsum, scales);
  wqrms_k<<<8192, 256, 0, stream>>>(qkv_w, out_w, scales, x, ada, Wq8, Wo8, Aq8, ascale);
  gemm_i8<<<768, 256, 0, stream>>>(Aq8, Wq8, 3072, 1024, 768, 0, ascale, &scales[0],
                                   nullptr, nullptr, qk, VT);
  prep_k<<<4096, 256, 0, stream>>>(qk, pos, scale, freqs, Qb, Kb);
  attn_k<<<512, 512, 0, stream>>>(Qb, Kb, VT, Opart, msb);
  oquant_k<<<4096, 256, 0, stream>>>(Opart, msb, Oq8, oscale);
  gemm_i8_n64<<<512, 256, 0, stream>>>(Oq8, Wo8, 1024, 1024, 512, oscale, &scales[2],
                                       x, out);
}